// Round 3
// baseline (3498.392 us; speedup 1.0000x reference)
//
#include <hip/hip_runtime.h>
#include <hip/hip_bf16.h>
#include <math.h>

typedef __bf16 bf16x8 __attribute__((ext_vector_type(8)));
typedef float  f32x4  __attribute__((ext_vector_type(4)));

#define MFMA(a,b,c) __builtin_amdgcn_mfma_f32_16x16x32_bf16(a, b, c, 0, 0, 0)
#define LOG2E 1.4426950408889634f

// ---------------- workspace float offsets ----------------
static constexpr size_t OFF_R0    = 0;                       // 12,582,912 : gates(f,b) then qkv buffer
static constexpr size_t OFF_GXT   = 12582912;                // 8,388,608 : accum+final
static constexpr size_t OFF_ACCUM = OFF_GXT;                 // 4,194,304
static constexpr size_t OFF_FINAL = OFF_GXT + 4194304;       // 4,194,304
static constexpr size_t SOFF      = OFF_GXT + 8388608;
static constexpr size_t OFF_ROWSUM= SOFF;                    // 32768
static constexpr size_t OFF_COLW  = OFF_ROWSUM + 32768;      // 524288 (16 deterministic partials)
static constexpr size_t OFF_ACM   = OFF_COLW + 524288;       // 4096
static constexpr size_t OFF_XMEAN = OFF_ACM + 4096;          // 4096
static constexpr size_t OFF_LC    = OFF_XMEAN + 4096;        // 2048
static constexpr size_t OFF_COEF  = OFF_LC + 2048;           // 256
static constexpr size_t OFF_GMIX  = OFF_COEF + 256;          // 16
static constexpr size_t OFF_MW    = OFF_GMIX + 16;           // 4
static constexpr size_t OFF_CONV9 = OFF_MW + 4;              // 5184
static constexpr size_t OFF_CBIAS = OFF_CONV9 + 5184;        // 64
static constexpr size_t OFF_WEFF  = OFF_CBIAS + 64;          // 4096 (8*16*16 complex)
static constexpr size_t OFF_PPOW  = OFF_WEFF + 4096;         // 1536
static constexpr size_t OFF_LBIAS = OFF_PPOW + 1536;         // 1024
static constexpr size_t OFF_W2    = OFF_LBIAS + 1024;        // 2048 (64*16 complex, e^{-i})
static constexpr size_t OFF_W1CS  = OFF_W2 + 2048;           // 16384 floats = bf16[32][1024]
static constexpr size_t OFF_W1T   = OFF_W1CS + 16384;        // 16384 floats = bf16[1024][32]
static constexpr size_t OFF_HB    = OFF_W1T + 16384;         // 131072 floats = bf16[128][2048]

__device__ __forceinline__ float sigm(float x){ return 1.0f/(1.0f + exp2f(-LOG2E*x)); }
__device__ __forceinline__ float tanhx(float x){ return 2.0f/(1.0f + exp2f(-2.0f*LOG2E*x)) - 1.0f; }
__device__ __forceinline__ unsigned pk2(float a, float b){
  union { __bf16 h[2]; unsigned u; } z; z.h[0]=(__bf16)a; z.h[1]=(__bf16)b; return z.u;
}
__device__ __forceinline__ void powpair(float t, float p, float& pos, float& neg){
  float a = fabsf(t);
  float v = (a > 0.f) ? exp2f(p * __log2f(a)) : 0.f;
  pos = (t > 0.f) ? v : 0.f;
  neg = (t < 0.f) ? v : 0.f;
}
__device__ __forceinline__ f32x4 fz4(){ return (f32x4){0.f,0.f,0.f,0.f}; }

// ---------------- constants / tables ----------------
__global__ void k_const(const float* __restrict__ ge_b1, const float* __restrict__ ge_w2,
                        const float* __restrict__ ge_b2, const float* __restrict__ mode_w,
                        const float* __restrict__ w5, const float* __restrict__ b5,
                        const float* __restrict__ w7, const float* __restrict__ b7,
                        const float* __restrict__ w9, const float* __restrict__ b9,
                        const float* __restrict__ pos_sw, const float* __restrict__ neg_sw,
                        const float* __restrict__ spw,
                        const float* __restrict__ bih_f, const float* __restrict__ bhh_f,
                        const float* __restrict__ bih_b, const float* __restrict__ bhh_b,
                        float* __restrict__ ws){
  int tid = threadIdx.x; // 256
  __shared__ float mw[3];
  __shared__ float tgh[256];
  __shared__ float sbuf[16];
  tgh[tid] = tanhf(ge_b1[tid]);
  if (tid == 0){
    float m0=mode_w[0], m1=mode_w[1], m2=mode_w[2];
    float mx = fmaxf(m0, fmaxf(m1,m2));
    float e0=expf(m0-mx), e1=expf(m1-mx), e2=expf(m2-mx);
    float s = e0+e1+e2;
    mw[0]=e0/s; mw[1]=e1/s; mw[2]=e2/s;
    ws[OFF_MW+0]=mw[0]; ws[OFF_MW+1]=mw[1]; ws[OFF_MW+2]=mw[2];
  }
  __syncthreads();
  if (tid < 16){
    float s = ge_b2[tid];
    for (int i=0;i<256;++i) s += ge_w2[tid*256+i]*tgh[i];
    sbuf[tid] = s;
  }
  __syncthreads();
  if (tid < 8){
    float a = sbuf[2*tid], b = sbuf[2*tid+1];
    float m = fmaxf(a,b);
    float ea = expf(a-m), eb = expf(b-m);
    ws[OFF_GMIX+2*tid]   = ea/(ea+eb);
    ws[OFF_GMIX+2*tid+1] = eb/(ea+eb);
  }
  for (int j=tid;j<512;j+=256){
    ws[OFF_LBIAS+j]     = bih_f[j]+bhh_f[j];
    ws[OFF_LBIAS+512+j] = bih_b[j]+bhh_b[j];
  }
  for (int f=tid; f<5184; f+=256){
    int d=f/81, t=f%81, ky=t/9, kx=t%9, dy=ky-4, dx=kx-4;
    float v = mw[2]*w9[d*81+t];
    if (dy>=-3 && dy<=3 && dx>=-3 && dx<=3) v += mw[1]*w7[d*49 + (dy+3)*7 + (dx+3)];
    if (dy>=-2 && dy<=2 && dx>=-2 && dx<=2) v += mw[0]*w5[d*25 + (dy+2)*5 + (dx+2)];
    ws[OFF_CONV9+f] = v;
  }
  if (tid<64) ws[OFF_CBIAS+tid] = mw[0]*b5[tid]+mw[1]*b7[tid]+mw[2]*b9[tid];
  // w_eff = wp + (1/16) wn   (softmax(spec_mix).mean(-1) == 1/16 exactly)
  for (int f=tid; f<2048; f+=256){
    int h=f>>8, k1=(f>>4)&15, k2=f&15;
    int src = ((h*16+k1)*64 + k2)*2;
    ws[OFF_WEFF+2*f]   = pos_sw[src]   + 0.0625f*neg_sw[src];
    ws[OFF_WEFF+2*f+1] = pos_sw[src+1] + 0.0625f*neg_sw[src+1];
  }
  for (int f=tid; f<1536; f+=256) ws[OFF_PPOW+f] = 1.0f + fabsf(spw[f]);
  // W2 (64x16 complex e^{-i 2pi e k2/64})
  for (int f=tid; f<1024; f+=256){
    int e=f>>4, k2=f&15; int ph=(e*k2)&63;
    float th = (float)ph * (6.283185307179586f/64.0f);
    ws[OFF_W2+2*f]   = cosf(th);
    ws[OFF_W2+2*f+1] = -sinf(th);
  }
  // W1CS bf16 [32][1024]: rows 0..15 cos, rows 16..31 -sin  (forward DFT)
  __bf16* w1cs = (__bf16*)(ws + OFF_W1CS);
  for (int f=tid; f<32768; f+=256){
    int r=f>>10, m=f&1023; int k1=r&15; int ph=(k1*m)&1023;
    float th = (float)ph * (6.283185307179586f/1024.0f);
    w1cs[f] = (__bf16)((r<16)?cosf(th):-sinf(th));
  }
  // W1T bf16 [1024][32]: cols 0..15 cos, cols 16..31 +sin (inverse DFT)
  __bf16* w1t = (__bf16*)(ws + OFF_W1T);
  for (int f=tid; f<32768; f+=256){
    int n=f>>5, r=f&31; int k1=r&15; int ph=(k1*n)&1023;
    float th = (float)ph * (6.283185307179586f/1024.0f);
    w1t[f] = (__bf16)((r<16)?cosf(th):sinf(th));
  }
}

// ---------------- generic GEMM: C[M,N] = A[M,K] @ W[N,K]^T (+bias), fp32 io, bf16 mfma ----------------
__global__ __launch_bounds__(256,2) void k_gemm(const float* __restrict__ A, const float* __restrict__ W,
                                                const float* __restrict__ bias, float* __restrict__ C,
                                                int M, int N, int K){
  __shared__ __bf16 As[128][40];
  __shared__ __bf16 Ws[128][40];
  int tid = threadIdx.x;
  int n0 = blockIdx.x * 128, m0 = blockIdx.y * 128;
  int l = tid & 63, wid = tid >> 6, lr = l & 15, lg = l >> 4;
  int wr = wid >> 1, wc = wid & 1;
  f32x4 acc[4][4];
  #pragma unroll
  for (int i=0;i<4;++i){ acc[i][0]=fz4(); acc[i][1]=fz4(); acc[i][2]=fz4(); acc[i][3]=fz4(); }
  int srow = tid >> 1, sk = (tid & 1) * 16;
  const float* Ap = A + (size_t)(m0 + srow) * K + sk;
  const float* Wp = W + (size_t)(n0 + srow) * K + sk;
  for (int k0 = 0; k0 < K; k0 += 32){
    f32x4 a0=*(const f32x4*)(Ap), a1=*(const f32x4*)(Ap+4), a2=*(const f32x4*)(Ap+8), a3=*(const f32x4*)(Ap+12);
    f32x4 w0=*(const f32x4*)(Wp), w1=*(const f32x4*)(Wp+4), w2=*(const f32x4*)(Wp+8), w3=*(const f32x4*)(Wp+12);
    Ap += 32; Wp += 32;
    __syncthreads();
    bf16x8 va, vb, wa, wb;
    #pragma unroll
    for (int j=0;j<4;++j){ va[j]=(__bf16)a0[j]; va[j+4]=(__bf16)a1[j]; vb[j]=(__bf16)a2[j]; vb[j+4]=(__bf16)a3[j];
                           wa[j]=(__bf16)w0[j]; wa[j+4]=(__bf16)w1[j]; wb[j]=(__bf16)w2[j]; wb[j+4]=(__bf16)w3[j]; }
    *(bf16x8*)&As[srow][sk]   = va;  *(bf16x8*)&As[srow][sk+8] = vb;
    *(bf16x8*)&Ws[srow][sk]   = wa;  *(bf16x8*)&Ws[srow][sk+8] = wb;
    __syncthreads();
    bf16x8 aF[4], bF[4];
    #pragma unroll
    for (int mf=0;mf<4;++mf) aF[mf] = *(const bf16x8*)&As[wr*64+mf*16+lr][lg*8];
    #pragma unroll
    for (int nf=0;nf<4;++nf) bF[nf] = *(const bf16x8*)&Ws[wc*64+nf*16+lr][lg*8];
    #pragma unroll
    for (int mf=0;mf<4;++mf)
      #pragma unroll
      for (int nf=0;nf<4;++nf) acc[mf][nf] = MFMA(aF[mf], bF[nf], acc[mf][nf]);
  }
  #pragma unroll
  for (int mf=0;mf<4;++mf)
    #pragma unroll
    for (int nf=0;nf<4;++nf){
      int row = m0 + wr*64 + mf*16 + lg*4;
      int col = n0 + wc*64 + nf*16 + lr;
      float bv = bias ? bias[col] : 0.f;
      #pragma unroll
      for (int r=0;r<4;++r) C[(size_t)(row+r)*N + col] = acc[mf][nf][r] + bv;
    }
}

// ---------------- LSTM scan: 16 blocks = 2 dir x 8 batch, raw-barrier pipeline ----------------
__global__ __launch_bounds__(256,1) void k_lstm_scan(const float* __restrict__ whh_f,
                                                     const float* __restrict__ whh_b,
                                                     const float* __restrict__ gates,
                                                     float* __restrict__ lc){
  int dir = blockIdx.x >> 3, b = blockIdx.x & 7;
  const float* __restrict__ whh = dir ? whh_b : whh_f;
  const float* gx0 = gates + (size_t)dir*4194304 + (size_t)b*524288;
  int tid=threadIdx.x, w=tid>>6, l=tid&63, lr=l&15, lg=l>>4;
  // weight fragments: A[row = g*128 + w*32 + hb*16 + lr][k = kc*32 + lg*8 + j]
  bf16x8 wf[4][2][4];
  #pragma unroll
  for (int g=0; g<4; ++g)
    #pragma unroll
    for (int hb=0; hb<2; ++hb)
      #pragma unroll
      for (int kc=0; kc<4; ++kc){
        const float* p = whh + (size_t)(g*128 + w*32 + hb*16 + lr)*128 + kc*32 + lg*8;
        bf16x8 v;
        #pragma unroll
        for (int j=0;j<8;++j) v[j]=(__bf16)p[j];
        wf[g][hb][kc]=v;
      }
  // lane -> hidden assignment (2-way redundant over l&8)
  int hb_sel = l&1, rsel=(l>>1)&3;
  int hloc = lg*4 + rsel;               // 0..15
  int hidden = w*32 + hb_sel*16 + hloc; // 0..127
  const float* gp = gx0 + (dir ? 1023*512 : 0) + hidden;
  int gstride = dir ? -512 : 512;
  __shared__ __bf16 hlds[2][128];
  if (tid<128){ hlds[0][tid]=(__bf16)0.f; hlds[1][tid]=(__bf16)0.f; }
  __syncthreads();
  float cst=0.f, hs=0.f;
  // 4-step-deep rotating gx prefetch (stays in flight across raw barriers)
  f32x4 gxr[4];
  #pragma unroll
  for (int j=0;j<4;++j){
    f32x4 v; v[0]=gp[0]; v[1]=gp[128]; v[2]=gp[256]; v[3]=gp[384];
    gxr[j]=v; gp += gstride;
  }

#define LSTM_STEP(J, RB, WB) { \
    asm volatile("s_waitcnt lgkmcnt(0)" ::: "memory"); \
    __builtin_amdgcn_sched_barrier(0); \
    __builtin_amdgcn_s_barrier(); \
    __builtin_amdgcn_sched_barrier(0); \
    bf16x8 hf[4]; \
    _Pragma("unroll") \
    for (int kc=0; kc<4; ++kc) hf[kc] = *(const bf16x8*)&hlds[RB][kc*32 + lg*8]; \
    f32x4 acc[4][2]; \
    _Pragma("unroll") \
    for (int g=0; g<4; ++g){ acc[g][0]=fz4(); acc[g][1]=fz4(); } \
    _Pragma("unroll") \
    for (int kc=0; kc<4; ++kc) \
      _Pragma("unroll") \
      for (int g=0; g<4; ++g){ \
        acc[g][0] = MFMA(wf[g][0][kc], hf[kc], acc[g][0]); \
        acc[g][1] = MFMA(wf[g][1][kc], hf[kc], acc[g][1]); } \
    f32x4 gnew; gnew[0]=gp[0]; gnew[1]=gp[128]; gnew[2]=gp[256]; gnew[3]=gp[384]; \
    gp += gstride; \
    float gv[4]; \
    _Pragma("unroll") \
    for (int g=0; g<4; ++g){ \
      f32x4 va = hb_sel ? acc[g][1] : acc[g][0]; \
      float x01 = (rsel&1) ? va[1] : va[0]; \
      float x23 = (rsel&1) ? va[3] : va[2]; \
      gv[g] = ((rsel&2) ? x23 : x01) + gxr[J][g]; } \
    gxr[J] = gnew; \
    float si=sigm(gv[0]), sf=sigm(gv[1]), tg=tanhx(gv[2]), so=sigm(gv[3]); \
    cst = sf*cst + si*tg; \
    float hv = so*tanhx(cst); \
    hs += hv; \
    if (!(l&8)) hlds[WB][hidden] = (__bf16)hv; }

  for (int it=0; it<256; ++it){
    LSTM_STEP(0, 0, 1)
    LSTM_STEP(1, 1, 0)
    LSTM_STEP(2, 0, 1)
    LSTM_STEP(3, 1, 0)
  }
#undef LSTM_STEP
  if (!(l&8)) lc[b*256 + dir*128 + hidden] = hs*(1.f/1024.f);
}

// ---------------- MHA: two-sweep softmax column weights ----------------
template<int MODE>
__global__ __launch_bounds__(256,1) void k_mha(const float* __restrict__ qkv, float* __restrict__ rowsum,
                                               float* __restrict__ colw){
  int rb = blockIdx.x, h2 = blockIdx.y, b = blockIdx.z;
  __shared__ __bf16 Qs[256][136];
  __shared__ __bf16 Ks[128][136];
  int tid=threadIdx.x, l=tid&63, w=tid>>6, lr=l&15, lg=l>>4;
  {
    const float qs = LOG2E / sqrtf(128.0f);
    int row = tid;
    const float* p = qkv + ((size_t)(b*1024 + rb*256 + row))*1536 + h2*128;
    #pragma unroll
    for (int cc=0; cc<128; cc+=8){
      f32x4 u0 = *(const f32x4*)(p+cc), u1 = *(const f32x4*)(p+cc+4);
      bf16x8 v;
      #pragma unroll
      for (int j=0;j<4;++j){ v[j]=(__bf16)(u0[j]*qs); v[j+4]=(__bf16)(u1[j]*qs); }
      *(bf16x8*)&Qs[row][cc] = v;
    }
  }
  float rs[4][4];
  if (MODE==1){
    #pragma unroll
    for (int mf=0;mf<4;++mf){ rs[mf][0]=0.f; rs[mf][1]=0.f; rs[mf][2]=0.f; rs[mf][3]=0.f; }
  } else {
    #pragma unroll
    for (int mf=0;mf<4;++mf)
      #pragma unroll
      for (int r=0;r<4;++r)
        rs[mf][r] = 1.0f / rowsum[((size_t)(b*4+h2))*1024 + rb*256 + w*64 + mf*16 + lg*4 + r];
  }
  for (int mc=0; mc<8; ++mc){
    __syncthreads();
    {
      int row = tid>>1, co = (tid&1)*64;
      const float* p = qkv + ((size_t)(b*1024 + mc*128 + row))*1536 + 512 + h2*128 + co;
      #pragma unroll
      for (int cc=0; cc<64; cc+=8){
        f32x4 u0 = *(const f32x4*)(p+cc), u1 = *(const f32x4*)(p+cc+4);
        bf16x8 v;
        #pragma unroll
        for (int j=0;j<4;++j){ v[j]=(__bf16)u0[j]; v[j+4]=(__bf16)u1[j]; }
        *(bf16x8*)&Ks[row][co+cc] = v;
      }
    }
    __syncthreads();
    f32x4 acc[4][8];
    #pragma unroll
    for (int mf=0;mf<4;++mf)
      #pragma unroll
      for (int nf=0;nf<8;++nf) acc[mf][nf]=fz4();
    #pragma unroll
    for (int ks=0;ks<4;++ks){
      bf16x8 aF[4], bFv[8];
      #pragma unroll
      for (int mf=0;mf<4;++mf) aF[mf] = *(const bf16x8*)&Qs[w*64+mf*16+lr][ks*32+lg*8];
      #pragma unroll
      for (int nf=0;nf<8;++nf) bFv[nf] = *(const bf16x8*)&Ks[nf*16+lr][ks*32+lg*8];
      #pragma unroll
      for (int mf=0;mf<4;++mf)
        #pragma unroll
        for (int nf=0;nf<8;++nf) acc[mf][nf] = MFMA(aF[mf], bFv[nf], acc[mf][nf]);
    }
    if (MODE==1){
      #pragma unroll
      for (int mf=0;mf<4;++mf)
        #pragma unroll
        for (int nf=0;nf<8;++nf)
          #pragma unroll
          for (int r=0;r<4;++r) rs[mf][r] += exp2f(acc[mf][nf][r]);
    } else {
      #pragma unroll
      for (int nf=0;nf<8;++nf){
        float cv = 0.f;
        #pragma unroll
        for (int mf=0;mf<4;++mf)
          #pragma unroll
          for (int r=0;r<4;++r) cv += exp2f(acc[mf][nf][r])*rs[mf][r];
        cv += __shfl_xor(cv,16);
        cv += __shfl_xor(cv,32);
        if (lg==0)
          colw[(((size_t)(rb*4+w)*8 + b)*4 + h2)*1024 + mc*128 + nf*16 + lr] = cv;
      }
    }
  }
  if (MODE==1){
    #pragma unroll
    for (int mf=0;mf<4;++mf)
      #pragma unroll
      for (int r=0;r<4;++r){
        float v = rs[mf][r];
        v += __shfl_xor(v,1); v += __shfl_xor(v,2); v += __shfl_xor(v,4); v += __shfl_xor(v,8);
        if (lr==0) rowsum[((size_t)(b*4+h2))*1024 + rb*256 + w*64 + mf*16 + lg*4 + r] = v;
      }
  }
}

__global__ void k_mha3(const float* __restrict__ qkv, const float* __restrict__ colw, float* __restrict__ acm){
  int h2 = blockIdx.x & 3, b = blockIdx.x >> 2;
  int tid = threadIdx.x;
  __shared__ float cwred[1024];
  for (int m=tid; m<1024; m+=256){
    float cw=0.f;
    #pragma unroll
    for (int t16=0;t16<16;++t16) cw += colw[(((size_t)t16*8 + b)*4 + h2)*1024 + m];
    cwred[m]=cw;
  }
  __syncthreads();
  int e = tid & 127, half = tid >> 7;
  float s = 0.f;
  for (int m = half*512; m < half*512+512; ++m)
    s += cwred[m] * qkv[((size_t)(b*1024+m))*1536 + 1024 + h2*128 + e];
  __shared__ float red[256];
  red[tid]=s; __syncthreads();
  if (tid<128) acm[((size_t)(b*4+h2))*128 + e] = (red[tid]+red[tid+128])*(1.f/1024.f);
}

__global__ void k_xmean(const float* __restrict__ x, float* __restrict__ xmean){
  int b = blockIdx.x, c = threadIdx.x; // 512
  float s=0.f;
  for (int n=0;n<1024;++n) s += x[((size_t)(b*1024+n))*512 + c];
  xmean[b*512+c] = s*(1.f/1024.f);
}

__global__ __launch_bounds__(256) void k_coeffs(float* __restrict__ ws,
                        const float* __restrict__ mow, const float* __restrict__ mob,
                        const float* __restrict__ ca_w1, const float* __restrict__ ca_b1,
                        const float* __restrict__ ca_w2, const float* __restrict__ ca_b2){
  int b = blockIdx.x, tid = threadIdx.x;
  __shared__ float av[512], comb[512], hid[256];
  for (int i=tid;i<512;i+=256) av[i] = ws[OFF_ACM + b*512 + i];
  __syncthreads();
  for (int c=tid;c<512;c+=256){
    float s = mob[c];
    for (int k=0;k<512;++k) s += mow[(size_t)c*512+k]*av[k];
    comb[c] = s + ws[OFF_XMEAN + b*512 + c] + ((c<256) ? ws[OFF_LC + b*256 + c] : 0.f);
  }
  __syncthreads();
  for (int j=tid;j<256;j+=256){
    float s = ca_b1[j];
    for (int k=0;k<512;++k) s += ca_w1[(size_t)j*512+k]*comb[k];
    hid[j] = fmaxf(s,0.f);
  }
  __syncthreads();
  if (tid<32){
    float s = ca_b2[tid];
    for (int k=0;k<256;++k) s += ca_w2[tid*256+k]*hid[k];
    ws[OFF_COEF + b*32 + tid] = 1.f/(1.f+expf(-s));
  }
}

// ---------------- spectral: forward DFT + filter -> Hb ----------------
__global__ __launch_bounds__(256,2) void k_spec1(const float* __restrict__ qkv, float* __restrict__ ws){
  int qk = blockIdx.x, h = blockIdx.y, b = blockIdx.z;
  int colbase = qk*512 + h*64;
  int tid=threadIdx.x, l=tid&63, w=tid>>6, lr=l&15, lg=l>>4;
  __shared__ __bf16 tT[64][520];
  __shared__ float M1[32][64];
  __shared__ float G2[256][2];
  const __bf16* w1cs = (const __bf16*)(ws + OFF_W1CS);
  f32x4 acc[2]; acc[0]=fz4(); acc[1]=fz4();
  for (int c0=0; c0<2; ++c0){
    __syncthreads();
    {
      int p = tid;
      int m0 = c0*512 + 2*p;
      const float* r0 = qkv + ((size_t)(b*1024 + m0))*1536 + colbase;
      const float* r1 = r0 + 1536;
      #pragma unroll
      for (int e=0;e<64;e+=4){
        f32x4 u0 = *(const f32x4*)(r0+e);
        f32x4 u1 = *(const f32x4*)(r1+e);
        #pragma unroll
        for (int j=0;j<4;++j) *(unsigned*)&tT[e+j][2*p] = pk2(u0[j], u1[j]);
      }
    }
    __syncthreads();
    for (int ks=0; ks<16; ++ks){
      bf16x8 bf = *(const bf16x8*)&tT[w*16+lr][ks*32+lg*8];
      #pragma unroll
      for (int mf=0;mf<2;++mf){
        bf16x8 af = *(const bf16x8*)(w1cs + (size_t)(mf*16+lr)*1024 + c0*512 + ks*32 + lg*8);
        acc[mf] = MFMA(af, bf, acc[mf]);
      }
    }
  }
  #pragma unroll
  for (int mf=0;mf<2;++mf)
    #pragma unroll
    for (int r=0;r<4;++r) M1[mf*16 + lg*4 + r][w*16 + lr] = acc[mf][r];
  __syncthreads();
  {
    int k1 = tid>>4, k2 = tid&15;
    float tfr=0.f, tfi=0.f;
    const float* w2 = ws + OFF_W2;
    for (int e=0;e<64;++e){
      float mr = M1[k1][e], mi = M1[16+k1][e];
      float cr = w2[(e*16+k2)*2], ci = w2[(e*16+k2)*2+1];
      tfr += mr*cr - mi*ci;
      tfi += mr*ci + mi*cr;
    }
    float wr = ws[OFF_WEFF + ((size_t)h*256 + k1*16 + k2)*2];
    float wi = ws[OFF_WEFF + ((size_t)h*256 + k1*16 + k2)*2 + 1];
    G2[tid][0] = tfr*wr - tfi*wi;
    G2[tid][1] = tfr*wi + tfi*wr;
  }
  __syncthreads();
  __bf16* hb = (__bf16*)(ws + OFF_HB) + ((size_t)((b*8+h)*2+qk))*2048;
  const float* w2 = ws + OFF_W2;
  for (int f=tid; f<1024; f+=256){
    int k1 = f>>6, d = f&63;
    float hr=0.f, hi=0.f;
    #pragma unroll
    for (int k2=0;k2<16;++k2){
      float gr=G2[k1*16+k2][0], gi=G2[k1*16+k2][1];
      float sc = k2 ? 2.f : 1.f;
      float cr = sc*w2[(d*16+k2)*2];
      float ci = -sc*w2[(d*16+k2)*2+1];
      hr += gr*cr - gi*ci;
      hi += gr*ci + gi*cr;
    }
    const float inv = 1.0f/65536.0f;
    hb[d*32 + k1]      = (__bf16)(hr*inv);
    hb[d*32 + 16 + k1] = (__bf16)(-hi*inv);
  }
}

// ---------------- spectral: inverse DFT apply (overwrite q/k) ----------------
__global__ __launch_bounds__(256,2) void k_spec2(float* __restrict__ qkv, const float* __restrict__ ws){
  int qk=blockIdx.x, h=blockIdx.y, b=blockIdx.z;
  int colbase = qk*512 + h*64;
  int tid=threadIdx.x, l=tid&63, w=tid>>6, lr=l&15, lg=l>>4;
  __shared__ __bf16 hbl[2048];
  const __bf16* hb = (const __bf16*)(ws + OFF_HB) + ((size_t)((b*8+h)*2+qk))*2048;
  *(bf16x8*)&hbl[tid*8] = *(const bf16x8*)&hb[tid*8];
  __syncthreads();
  const __bf16* w1t = (const __bf16*)(ws + OFF_W1T);
  bf16x8 bF[4];
  #pragma unroll
  for (int nf=0;nf<4;++nf) bF[nf] = *(const bf16x8*)&hbl[(nf*16+lr)*32 + lg*8];
  for (int pass=0; pass<4; ++pass){
    int rowbase = w*256 + pass*64;
    f32x4 acc[4][4];
    #pragma unroll
    for (int mf=0;mf<4;++mf){ acc[mf][0]=fz4(); acc[mf][1]=fz4(); acc[mf][2]=fz4(); acc[mf][3]=fz4(); }
    #pragma unroll
    for (int mf=0;mf<4;++mf){
      bf16x8 aF = *(const bf16x8*)(w1t + (size_t)(rowbase+mf*16+lr)*32 + lg*8);
      #pragma unroll
      for (int nf=0;nf<4;++nf) acc[mf][nf] = MFMA(aF, bF[nf], acc[mf][nf]);
    }
    #pragma unroll
    for (int mf=0;mf<4;++mf)
      #pragma unroll
      for (int nf=0;nf<4;++nf)
        #pragma unroll
        for (int r=0;r<4;++r){
          int n = rowbase + mf*16 + lg*4 + r;
          int d = nf*16 + lr;
          qkv[((size_t)(b*1024+n))*1536 + colbase + d] = acc[mf][nf][r];
        }
  }
}

// ---------------- polarity linear attention ----------------
__global__ __launch_bounds__(256,1) void k_polar(const float* __restrict__ qkv, const float* __restrict__ ws,
                                                 float* __restrict__ accum, int s){
  int h = blockIdx.x, b = blockIdx.y;
  int tid=threadIdx.x, l=tid&63, w=tid>>6, lr=l&15, lg=l>>4;
  __shared__ float plds[23200];
  __bf16* kpT = (__bf16*)plds;
  __bf16* knT = (__bf16*)((char*)plds + 17408);
  __bf16* vT  = (__bf16*)((char*)plds + 34816);
  float* scal = (float*)((char*)plds + 92416);
  float* pvs  = scal + 8;
  if (tid<4)  scal[tid] = ws[OFF_COEF + b*32 + h*4 + tid];
  if (tid==4) scal[4] = ws[OFF_GMIX + 2*h];
  if (tid==5) scal[5] = ws[OFF_GMIX + 2*h+1];
  if (tid<64) pvs[tid] = ws[OFF_PPOW + ((size_t)s*8+h)*64 + tid];
  for (int i=tid; i<16*136; i+=256) vT[64*136 + i] = (__bf16)((i<136)?1.0f:0.0f);
  f32x4 acc[4][5];
  #pragma unroll
  for (int mf=0;mf<4;++mf)
    #pragma unroll
    for (int nf=0;nf<5;++nf) acc[mf][nf]=fz4();
  for (int mc=0;mc<8;++mc){
    __syncthreads();
    #pragma unroll
    for (int it=0; it<16; ++it){
      int flat = tid + 256*it;
      int d = flat & 63, np = flat >> 6;
      int n = mc*128 + 2*np;
      const float* kr = qkv + ((size_t)(b*1024+n))*1536 + 512 + h*64 + d;
      const float* vr = qkv + ((size_t)(b*1024+n))*1536 + 1024 + h*64 + d;
      float p = pvs[d];
      float k0=kr[0], k1=kr[1536], v0=vr[0], v1=vr[1536];
      float kp0,kn0,kp1,kn1;
      powpair(k0,p,kp0,kn0); powpair(k1,p,kp1,kn1);
      *(unsigned*)&kpT[d*136 + 2*np] = pk2(kp0,kp1);
      *(unsigned*)&knT[d*136 + 2*np] = pk2(kn0,kn1);
      *(unsigned*)&vT [d*136 + 2*np] = pk2(v0,v1);
    }
    __syncthreads();
    const __bf16* A = (w&2)?knT:kpT;
    int kh = (w&1)*64;
    #pragma unroll
    for (int ks=0;ks<2;++ks){
      bf16x8 aF[4];
      #pragma unroll
      for (int mf=0;mf<4;++mf) aF[mf] = *(const bf16x8*)&A[(mf*16+lr)*136 + kh + ks*32 + lg*8];
      #pragma unroll
      for (int nf=0;nf<5;++nf){
        bf16x8 bFv = *(const bf16x8*)&vT[(nf*16+lr)*136 + kh + ks*32 + lg*8];
        #pragma unroll
        for (int mf=0;mf<4;++mf) acc[mf][nf] = MFMA(aF[mf], bFv, acc[mf][nf]);
      }
    }
  }
  __syncthreads();
  float* kvf = plds; // [2][64][80]
  if ((w&1)==0){
    int mat = w>>1;
    #pragma unroll
    for (int mf=0;mf<4;++mf)
      #pragma unroll
      for (int nf=0;nf<5;++nf)
        #pragma unroll
        for (int r=0;r<4;++r)
          kvf[((size_t)mat*64 + mf*16+lg*4+r)*80 + nf*16+lr] = acc[mf][nf][r];
  }
  __syncthreads();
  if (w&1){
    int mat = w>>1;
    #pragma unroll
    for (int mf=0;mf<4;++mf)
      #pragma unroll
      for (int nf=0;nf<5;++nf)
        #pragma unroll
        for (int r=0;r<4;++r)
          kvf[((size_t)mat*64 + mf*16+lg*4+r)*80 + nf*16+lr] += acc[mf][nf][r];
  }
  __syncthreads();
  __bf16* Bm = (__bf16*)((char*)plds + 69632);
  {
    float c0=scal[0], c1=scal[1], c2=scal[2], c3=scal[3], g0=scal[4], g1=scal[5];
    for (int f=tid; f<80*128; f+=256){
      int e=f>>7, kk=f&127;
      float v;
      if (e<64){
        if (kk<64) v = g0*c0*kvf[kk*80+e] + g1*c2*kvf[(64+kk)*80+e];
        else { int k2=kk-64; v = g0*c1*kvf[(64+k2)*80+e] + g1*c3*kvf[k2*80+e]; }
      } else if (e==64){
        v = (kk<64) ? kvf[kk*80+64] : kvf[(64+(kk-64))*80+64];
      } else v = 0.f;
      Bm[e*136+kk] = (__bf16)v;
    }
  }
  __syncthreads();
  bf16x8 bF2[5][4];
  #pragma unroll
  for (int nf=0;nf<5;++nf)
    #pragma unroll
    for (int ks=0;ks<4;++ks) bF2[nf][ks] = *(const bf16x8*)&Bm[(nf*16+lr)*136 + ks*32 + lg*8];
  __bf16* At = (__bf16*)plds;
  float* zb = (float*)((char*)plds + 91392);
  for (int pass=0; pass<4; ++pass){
    __syncthreads();
    #pragma unroll
    for (int it=0; it<16; ++it){
      int flat = tid + 256*it;
      int row = flat>>4, dg = flat&15;
      int n = pass*256 + row;
      const float* qr = qkv + ((size_t)(b*1024+n))*1536 + h*64 + dg*4;
      f32x4 u = *(const f32x4*)qr;
      float qp[4], qn[4];
      #pragma unroll
      for (int j=0;j<4;++j) powpair(u[j], pvs[dg*4+j], qp[j], qn[j]);
      *(unsigned*)&At[row*136 + dg*4]        = pk2(qp[0],qp[1]);
      *(unsigned*)&At[row*136 + dg*4+2]      = pk2(qp[2],qp[3]);
      *(unsigned*)&At[row*136 + 64 + dg*4]   = pk2(qn[0],qn[1]);
      *(unsigned*)&At[row*136 + 64 + dg*4+2] = pk2(qn[2],qn[3]);
    }
    __syncthreads();
    f32x4 a2[4][5];
    #pragma unroll
    for (int mf=0;mf<4;++mf)
      #pragma unroll
      for (int nf=0;nf<5;++nf) a2[mf][nf]=fz4();
    #pragma unroll
    for (int ks=0;ks<4;++ks){
      bf16x8 aF[4];
      #pragma unroll
      for (int mf=0;mf<4;++mf) aF[mf] = *(const bf16x8*)&At[(w*64+mf*16+lr)*136 + ks*32 + lg*8];
      #pragma unroll
      for (int nf=0;nf<5;++nf)
        #pragma unroll
        for (int mf=0;mf<4;++mf) a2[mf][nf] = MFMA(aF[mf], bF2[nf][ks], a2[mf][nf]);
    }
    if (lr==0){
      #pragma unroll
      for (int mf=0;mf<4;++mf)
        #pragma unroll
        for (int r=0;r<4;++r) zb[w*64 + mf*16 + lg*4 + r] = a2[mf][4][r] + 1e-6f;
    }
    __syncthreads();
    #pragma unroll
    for (int mf=0;mf<4;++mf){
      float rz[4];
      #pragma unroll
      for (int r=0;r<4;++r) rz[r] = 1.0f / zb[w*64 + mf*16 + lg*4 + r];
      #pragma unroll
      for (int nf=0;nf<4;++nf)
        #pragma unroll
        for (int r=0;r<4;++r){
          int n = pass*256 + w*64 + mf*16 + lg*4 + r;
          int e = nf*16 + lr;
          size_t oi = ((size_t)((b*8+h)*1024) + n)*64 + e;
          float v = a2[mf][nf][r]*rz[r];
          if (s==0) accum[oi] = v; else accum[oi] += v;
        }
    }
  }
}

// ---------------- combined 9x9 depthwise conv ----------------
__global__ __launch_bounds__(256,2) void k_conv(const float* __restrict__ qkv, const float* __restrict__ ws,
                                                float* __restrict__ accum){
  int bid = blockIdx.x;
  int sl = bid & 3, h = (bid>>2)&7, b = bid>>5;
  int tid = threadIdx.x;
  __shared__ float vs[1024][16];
  __shared__ float wc[16][81];
  __shared__ float cb[16];
  for (int it=0; it<64; ++it){
    int flat = tid + 256*it;
    int c = flat & 15, pix = flat>>4;
    vs[pix][c] = qkv[((size_t)(b*1024+pix))*1536 + 1024 + h*64 + sl*16 + c];
  }
  for (int f=tid; f<16*81; f+=256) wc[f/81][f%81] = ws[OFF_CONV9 + (size_t)(sl*16 + f/81)*81 + (f%81)];
  if (tid<16) cb[tid] = ws[OFF_CBIAS + sl*16 + tid];
  __syncthreads();
  #pragma unroll
  for (int cc=0; cc<2; ++cc){
    int col = tid + 256*cc;
    int c = col & 15, x = col >> 4;
    float a[32];
    #pragma unroll
    for (int y=0;y<32;++y) a[y]=0.f;
    #pragma unroll
    for (int dx=-4; dx<=4; ++dx){
      int xx = x+dx;
      bool xv = (xx>=0)&&(xx<32);
      float colv[40];
      #pragma unroll
      for (int i=0;i<40;++i){
        int yy = i-4;
        colv[i] = (xv && yy>=0 && yy<32) ? vs[yy*32+xx][c] : 0.f;
      }
      #pragma unroll
      for (int dy=0; dy<9; ++dy){
        float wv = wc[c][dy*9 + dx+4];
        #pragma unroll
        for (int y=0;y<32;++y) a[y] += wv*colv[y+dy];
      }
    }
    float bias = cb[c];
    #pragma unroll
    for (int y=0;y<32;++y){
      size_t oi = ((size_t)((b*8+h)*1024) + y*32 + x)*64 + sl*16 + c;
      accum[oi] += a[y] + bias;
    }
  }
}

__global__ void k_finalize(const float* __restrict__ accum, float* __restrict__ fin){
  int idx = blockIdx.x*256 + threadIdx.x;
  int c = idx & 511, n = (idx>>9)&1023, b = idx>>19;
  int h = c>>6, d = c&63;
  fin[idx] = accum[((size_t)((b*8+h)*1024)+n)*64 + d] * (1.0f/3.0f);
}

// ---------------- launch ----------------
extern "C" void kernel_launch(void* const* d_in, const int* in_sizes, int n_in,
                              void* d_out, int out_size, void* d_ws, size_t ws_size,
                              hipStream_t stream){
  const float* x        = (const float*)d_in[0];
  const float* qkv_w    = (const float*)d_in[3];
  const float* proj_w   = (const float*)d_in[4];
  const float* proj_b   = (const float*)d_in[5];
  const float* pos_sw   = (const float*)d_in[6];
  const float* neg_sw   = (const float*)d_in[7];
  const float* ca_w1    = (const float*)d_in[9];
  const float* ca_b1    = (const float*)d_in[10];
  const float* ca_w2    = (const float*)d_in[11];
  const float* ca_b2    = (const float*)d_in[12];
  const float* wih_f    = (const float*)d_in[13];
  const float* whh_f    = (const float*)d_in[14];
  const float* bih_f    = (const float*)d_in[15];
  const float* bhh_f    = (const float*)d_in[16];
  const float* wih_b    = (const float*)d_in[17];
  const float* whh_b    = (const float*)d_in[18];
  const float* bih_b    = (const float*)d_in[19];
  const float* bhh_b    = (const float*)d_in[20];
  const float* mha_in_w = (const float*)d_in[21];
  const float* mha_in_b = (const float*)d_in[22];
  const float* mha_out_w= (const float*)d_in[23];
  const float* mha_out_b= (const float*)d_in[24];
  const float* ge_b1    = (const float*)d_in[26];
  const float* ge_w2    = (const float*)d_in[27];
  const float* ge_b2    = (const float*)d_in[28];
  const float* spw      = (const float*)d_in[29];
  const float* w5 = (const float*)d_in[30]; const float* b5 = (const float*)d_in[31];
  const float* w7 = (const float*)d_in[32]; const float* b7 = (const float*)d_in[33];
  const float* w9 = (const float*)d_in[34]; const float* b9 = (const float*)d_in[35];
  const float* mode_w = (const float*)d_in[36];
  float* ws  = (float*)d_ws;
  float* out = (float*)d_out;

  k_const<<<1,256,0,stream>>>(ge_b1, ge_w2, ge_b2, mode_w, w5,b5,w7,b7,w9,b9,
                              pos_sw, neg_sw, spw, bih_f,bhh_f,bih_b,bhh_b, ws);
  // LSTM input gemms (gates in (b,t,512))
  k_gemm<<<dim3(4,64),256,0,stream>>>(x, wih_f, ws+OFF_LBIAS,     ws+OFF_R0,          8192,512,512);
  k_gemm<<<dim3(4,64),256,0,stream>>>(x, wih_b, ws+OFF_LBIAS+512, ws+OFF_R0+4194304,  8192,512,512);
  k_lstm_scan<<<16,256,0,stream>>>(whh_f, whh_b, ws+OFF_R0, ws+OFF_LC);
  // MHA branch
  k_gemm<<<dim3(12,64),256,0,stream>>>(x, mha_in_w, mha_in_b, ws+OFF_R0, 8192,1536,512);
  k_mha<1><<<dim3(4,4,8),256,0,stream>>>(ws+OFF_R0, ws+OFF_ROWSUM, ws+OFF_COLW);
  k_mha<2><<<dim3(4,4,8),256,0,stream>>>(ws+OFF_R0, ws+OFF_ROWSUM, ws+OFF_COLW);
  k_mha3<<<32,256,0,stream>>>(ws+OFF_R0, ws+OFF_COLW, ws+OFF_ACM);
  k_xmean<<<8,512,0,stream>>>(x, ws+OFF_XMEAN);
  k_coeffs<<<8,256,0,stream>>>(ws, mha_out_w, mha_out_b, ca_w1, ca_b1, ca_w2, ca_b2);
  // scales
  for (int s=0; s<3; ++s){
    k_gemm<<<dim3(12,64),256,0,stream>>>(x, qkv_w + (size_t)s*1536*512, nullptr, ws+OFF_R0, 8192,1536,512);
    k_spec1<<<dim3(2,8,8),256,0,stream>>>(ws+OFF_R0, ws);
    k_spec2<<<dim3(2,8,8),256,0,stream>>>(ws+OFF_R0, ws);
    k_polar<<<dim3(8,8),256,0,stream>>>(ws+OFF_R0, ws, ws+OFF_ACCUM, s);
    k_conv<<<256,256,0,stream>>>(ws+OFF_R0, ws, ws+OFF_ACCUM);
  }
  k_finalize<<<16384,256,0,stream>>>(ws+OFF_ACCUM, ws+OFF_FINAL);
  k_gemm<<<dim3(4,64),256,0,stream>>>(ws+OFF_FINAL, proj_w, proj_b, out, 8192,512,512);
}

// Round 4
// 2442.310 us; speedup vs baseline: 1.4324x; 1.4324x over previous
//
#include <hip/hip_runtime.h>
#include <hip/hip_bf16.h>
#include <math.h>

typedef __bf16 bf16x8 __attribute__((ext_vector_type(8)));
typedef float  f32x4  __attribute__((ext_vector_type(4)));

#define MFMA(a,b,c) __builtin_amdgcn_mfma_f32_16x16x32_bf16(a, b, c, 0, 0, 0)
#define LOG2E 1.4426950408889634f

// ---------------- workspace float offsets ----------------
static constexpr size_t OFF_R0    = 0;                       // 12,582,912 : gates(f,b) then qkv buffer
static constexpr size_t OFF_GXT   = 12582912;                // 8,388,608 : gxt -> later accum+final
static constexpr size_t OFF_ACCUM = OFF_GXT;                 // 4,194,304
static constexpr size_t OFF_FINAL = OFF_GXT + 4194304;       // 4,194,304
static constexpr size_t SOFF      = OFF_GXT + 8388608;
static constexpr size_t OFF_ROWSUM= SOFF;                    // 32768
static constexpr size_t OFF_COLW  = OFF_ROWSUM + 32768;      // 524288 (16 deterministic partials)
static constexpr size_t OFF_ACM   = OFF_COLW + 524288;       // 4096
static constexpr size_t OFF_XMEAN = OFF_ACM + 4096;          // 4096
static constexpr size_t OFF_LC    = OFF_XMEAN + 4096;        // 2048
static constexpr size_t OFF_COEF  = OFF_LC + 2048;           // 256
static constexpr size_t OFF_GMIX  = OFF_COEF + 256;          // 16
static constexpr size_t OFF_MW    = OFF_GMIX + 16;           // 4
static constexpr size_t OFF_CONV9 = OFF_MW + 4;              // 5184
static constexpr size_t OFF_CBIAS = OFF_CONV9 + 5184;        // 64
static constexpr size_t OFF_WEFF  = OFF_CBIAS + 64;          // 4096 (8*16*16 complex)
static constexpr size_t OFF_PPOW  = OFF_WEFF + 4096;         // 1536
static constexpr size_t OFF_LBIAS = OFF_PPOW + 1536;         // 1024
static constexpr size_t OFF_W2    = OFF_LBIAS + 1024;        // 2048 (64*16 complex, e^{-i})
static constexpr size_t OFF_W1CS  = OFF_W2 + 2048;           // 16384 floats = bf16[32][1024]
static constexpr size_t OFF_W1T   = OFF_W1CS + 16384;        // 16384 floats = bf16[1024][32]
static constexpr size_t OFF_HB    = OFF_W1T + 16384;         // 131072 floats = bf16[128][2048]

__device__ __forceinline__ float sigm(float x){ return 1.0f/(1.0f + exp2f(-LOG2E*x)); }
__device__ __forceinline__ float tanhx(float x){ return 2.0f/(1.0f + exp2f(-2.0f*LOG2E*x)) - 1.0f; }
__device__ __forceinline__ unsigned pk2(float a, float b){
  union { __bf16 h[2]; unsigned u; } z; z.h[0]=(__bf16)a; z.h[1]=(__bf16)b; return z.u;
}
__device__ __forceinline__ void powpair(float t, float p, float& pos, float& neg){
  float a = fabsf(t);
  float v = (a > 0.f) ? exp2f(p * __log2f(a)) : 0.f;
  pos = (t > 0.f) ? v : 0.f;
  neg = (t < 0.f) ? v : 0.f;
}
__device__ __forceinline__ f32x4 fz4(){ return (f32x4){0.f,0.f,0.f,0.f}; }

// ---------------- constants / tables ----------------
__global__ void k_const(const float* __restrict__ ge_b1, const float* __restrict__ ge_w2,
                        const float* __restrict__ ge_b2, const float* __restrict__ mode_w,
                        const float* __restrict__ w5, const float* __restrict__ b5,
                        const float* __restrict__ w7, const float* __restrict__ b7,
                        const float* __restrict__ w9, const float* __restrict__ b9,
                        const float* __restrict__ pos_sw, const float* __restrict__ neg_sw,
                        const float* __restrict__ spw,
                        const float* __restrict__ bih_f, const float* __restrict__ bhh_f,
                        const float* __restrict__ bih_b, const float* __restrict__ bhh_b,
                        float* __restrict__ ws){
  int tid = threadIdx.x; // 256
  __shared__ float mw[3];
  __shared__ float tgh[256];
  __shared__ float sbuf[16];
  tgh[tid] = tanhf(ge_b1[tid]);
  if (tid == 0){
    float m0=mode_w[0], m1=mode_w[1], m2=mode_w[2];
    float mx = fmaxf(m0, fmaxf(m1,m2));
    float e0=expf(m0-mx), e1=expf(m1-mx), e2=expf(m2-mx);
    float s = e0+e1+e2;
    mw[0]=e0/s; mw[1]=e1/s; mw[2]=e2/s;
    ws[OFF_MW+0]=mw[0]; ws[OFF_MW+1]=mw[1]; ws[OFF_MW+2]=mw[2];
  }
  __syncthreads();
  if (tid < 16){
    float s = ge_b2[tid];
    for (int i=0;i<256;++i) s += ge_w2[tid*256+i]*tgh[i];
    sbuf[tid] = s;
  }
  __syncthreads();
  if (tid < 8){
    float a = sbuf[2*tid], b = sbuf[2*tid+1];
    float m = fmaxf(a,b);
    float ea = expf(a-m), eb = expf(b-m);
    ws[OFF_GMIX+2*tid]   = ea/(ea+eb);
    ws[OFF_GMIX+2*tid+1] = eb/(ea+eb);
  }
  for (int j=tid;j<512;j+=256){
    ws[OFF_LBIAS+j]     = bih_f[j]+bhh_f[j];
    ws[OFF_LBIAS+512+j] = bih_b[j]+bhh_b[j];
  }
  for (int f=tid; f<5184; f+=256){
    int d=f/81, t=f%81, ky=t/9, kx=t%9, dy=ky-4, dx=kx-4;
    float v = mw[2]*w9[d*81+t];
    if (dy>=-3 && dy<=3 && dx>=-3 && dx<=3) v += mw[1]*w7[d*49 + (dy+3)*7 + (dx+3)];
    if (dy>=-2 && dy<=2 && dx>=-2 && dx<=2) v += mw[0]*w5[d*25 + (dy+2)*5 + (dx+2)];
    ws[OFF_CONV9+f] = v;
  }
  if (tid<64) ws[OFF_CBIAS+tid] = mw[0]*b5[tid]+mw[1]*b7[tid]+mw[2]*b9[tid];
  // w_eff = wp + (1/16) wn   (softmax(spec_mix).mean(-1) == 1/16 exactly)
  for (int f=tid; f<2048; f+=256){
    int h=f>>8, k1=(f>>4)&15, k2=f&15;
    int src = ((h*16+k1)*64 + k2)*2;
    ws[OFF_WEFF+2*f]   = pos_sw[src]   + 0.0625f*neg_sw[src];
    ws[OFF_WEFF+2*f+1] = pos_sw[src+1] + 0.0625f*neg_sw[src+1];
  }
  for (int f=tid; f<1536; f+=256) ws[OFF_PPOW+f] = 1.0f + fabsf(spw[f]);
  // W2 (64x16 complex e^{-i 2pi e k2/64})
  for (int f=tid; f<1024; f+=256){
    int e=f>>4, k2=f&15; int ph=(e*k2)&63;
    float th = (float)ph * (6.283185307179586f/64.0f);
    ws[OFF_W2+2*f]   = cosf(th);
    ws[OFF_W2+2*f+1] = -sinf(th);
  }
  // W1CS bf16 [32][1024]: rows 0..15 cos, rows 16..31 -sin  (forward DFT)
  __bf16* w1cs = (__bf16*)(ws + OFF_W1CS);
  for (int f=tid; f<32768; f+=256){
    int r=f>>10, m=f&1023; int k1=r&15; int ph=(k1*m)&1023;
    float th = (float)ph * (6.283185307179586f/1024.0f);
    w1cs[f] = (__bf16)((r<16)?cosf(th):-sinf(th));
  }
  // W1T bf16 [1024][32]: cols 0..15 cos, cols 16..31 +sin (inverse DFT)
  __bf16* w1t = (__bf16*)(ws + OFF_W1T);
  for (int f=tid; f<32768; f+=256){
    int n=f>>5, r=f&31; int k1=r&15; int ph=(k1*n)&1023;
    float th = (float)ph * (6.283185307179586f/1024.0f);
    w1t[f] = (__bf16)((r<16)?cosf(th):sinf(th));
  }
}

// ---------------- generic GEMM: C[M,N] = A[M,K] @ W[N,K]^T (+bias), fp32 io, bf16 mfma ----------------
__global__ __launch_bounds__(256,2) void k_gemm(const float* __restrict__ A, const float* __restrict__ W,
                                                const float* __restrict__ bias, float* __restrict__ C,
                                                int M, int N, int K){
  __shared__ __bf16 As[128][40];
  __shared__ __bf16 Ws[128][40];
  int tid = threadIdx.x;
  int n0 = blockIdx.x * 128, m0 = blockIdx.y * 128;
  int l = tid & 63, wid = tid >> 6, lr = l & 15, lg = l >> 4;
  int wr = wid >> 1, wc = wid & 1;
  f32x4 acc[4][4];
  #pragma unroll
  for (int i=0;i<4;++i){ acc[i][0]=fz4(); acc[i][1]=fz4(); acc[i][2]=fz4(); acc[i][3]=fz4(); }
  int srow = tid >> 1, sk = (tid & 1) * 16;
  const float* Ap = A + (size_t)(m0 + srow) * K + sk;
  const float* Wp = W + (size_t)(n0 + srow) * K + sk;
  for (int k0 = 0; k0 < K; k0 += 32){
    f32x4 a0=*(const f32x4*)(Ap), a1=*(const f32x4*)(Ap+4), a2=*(const f32x4*)(Ap+8), a3=*(const f32x4*)(Ap+12);
    f32x4 w0=*(const f32x4*)(Wp), w1=*(const f32x4*)(Wp+4), w2=*(const f32x4*)(Wp+8), w3=*(const f32x4*)(Wp+12);
    Ap += 32; Wp += 32;
    __syncthreads();
    bf16x8 va, vb, wa, wb;
    #pragma unroll
    for (int j=0;j<4;++j){ va[j]=(__bf16)a0[j]; va[j+4]=(__bf16)a1[j]; vb[j]=(__bf16)a2[j]; vb[j+4]=(__bf16)a3[j];
                           wa[j]=(__bf16)w0[j]; wa[j+4]=(__bf16)w1[j]; wb[j]=(__bf16)w2[j]; wb[j+4]=(__bf16)w3[j]; }
    *(bf16x8*)&As[srow][sk]   = va;  *(bf16x8*)&As[srow][sk+8] = vb;
    *(bf16x8*)&Ws[srow][sk]   = wa;  *(bf16x8*)&Ws[srow][sk+8] = wb;
    __syncthreads();
    bf16x8 aF[4], bF[4];
    #pragma unroll
    for (int mf=0;mf<4;++mf) aF[mf] = *(const bf16x8*)&As[wr*64+mf*16+lr][lg*8];
    #pragma unroll
    for (int nf=0;nf<4;++nf) bF[nf] = *(const bf16x8*)&Ws[wc*64+nf*16+lr][lg*8];
    #pragma unroll
    for (int mf=0;mf<4;++mf)
      #pragma unroll
      for (int nf=0;nf<4;++nf) acc[mf][nf] = MFMA(aF[mf], bF[nf], acc[mf][nf]);
  }
  #pragma unroll
  for (int mf=0;mf<4;++mf)
    #pragma unroll
    for (int nf=0;nf<4;++nf){
      int row = m0 + wr*64 + mf*16 + lg*4;
      int col = n0 + wc*64 + nf*16 + lr;
      float bv = bias ? bias[col] : 0.f;
      #pragma unroll
      for (int r=0;r<4;++r) C[(size_t)(row+r)*N + col] = acc[mf][nf][r] + bv;
    }
}

// ---------------- transpose gates (b,t,j) -> (t,j,b) ----------------
__global__ void k_gxt(const float* __restrict__ gates, float* __restrict__ gxt){
  int t = blockIdx.x & 1023, dir = blockIdx.x >> 10;
  int tid = threadIdx.x;
  const float* g = gates + (size_t)dir*4194304;
  float* o = gxt + (size_t)dir*4194304 + (size_t)t*4096;
  for (int j=tid; j<512; j+=256){
    float vv[8];
    #pragma unroll
    for (int b=0;b<8;++b) vv[b] = g[((size_t)b*1024 + t)*512 + j];
    f32x4 u0 = {vv[0],vv[1],vv[2],vv[3]}, u1 = {vv[4],vv[5],vv[6],vv[7]};
    *(f32x4*)(o + (size_t)j*8)     = u0;
    *(f32x4*)(o + (size_t)j*8 + 4) = u1;
  }
}

// ---------------- LSTM scan v3: 2 blocks (dir) x 8 waves, batched-N MFMA, all lanes productive ----------------
// gxt layout: (dir, t, j(512), b(8)) f32.  h in LDS [2][8][132] bf16 (double-buffered).
__global__ __launch_bounds__(512,1) void k_lstm_scan(const float* __restrict__ whh_f,
                                                     const float* __restrict__ whh_b,
                                                     const float* __restrict__ gxt,
                                                     float* __restrict__ lc){
  int dir = blockIdx.x;
  const float* __restrict__ whh = dir ? whh_b : whh_f;
  const float* gx0 = gxt + (size_t)dir*4194304;
  int tid=threadIdx.x, w=tid>>6, l=tid&63;
  int lr=l&15, lg=l>>4;          // MFMA row/col-within-tile and k-group
  int b = l&7, half = (l>>3)&1;  // batch column (duplicated over bit3), row-pair select
  // Weight fragments: A[row = q*128 + w*16 + lr][k = kc*32 + lg*8 + e]
  bf16x8 wf[4][4];
  #pragma unroll
  for (int q=0;q<4;++q)
    #pragma unroll
    for (int kc=0;kc<4;++kc){
      const float* p = whh + (size_t)(q*128 + w*16 + lr)*128 + kc*32 + lg*8;
      bf16x8 v;
      #pragma unroll
      for (int j=0;j<8;++j) v[j]=(__bf16)p[j];
      wf[q][kc]=v;
    }
  __shared__ __bf16 hbuf[2][8][132];
  for (int i=tid; i<2*8*132; i+=512) ((__bf16*)hbuf)[i] = (__bf16)0.0f;
  int j0 = w*16 + lg*4 + half*2;      // this lane's two h rows: j0, j0+1
  int joff = j0*8 + b;                // gxt per-t offset base
  const float* ptr = gx0 + (dir ? (size_t)1023*4096 : 0);
  long tstride = dir ? -4096 : 4096;
  float cs0=0.f, cs1=0.f, hs0=0.f, hs1=0.f;
  float gA[8], gB[8];
  #pragma unroll
  for (int q=0;q<4;++q){ gA[q*2]=ptr[q*1024+joff]; gA[q*2+1]=ptr[q*1024+joff+8]; }
  ptr += tstride;
  #pragma unroll
  for (int q=0;q<4;++q){ gB[q*2]=ptr[q*1024+joff]; gB[q*2+1]=ptr[q*1024+joff+8]; }
  ptr += tstride;
  __syncthreads();

#define LSTM_STEP(RB, WB, G) { \
    float gq[8]; \
    _Pragma("unroll") for (int i=0;i<8;++i) gq[i]=G[i]; \
    _Pragma("unroll") for (int q=0;q<4;++q){ G[q*2]=ptr[q*1024+joff]; G[q*2+1]=ptr[q*1024+joff+8]; } \
    ptr += tstride; \
    bf16x8 hf[4]; \
    _Pragma("unroll") for (int kc=0;kc<4;++kc) hf[kc] = *(const bf16x8*)&hbuf[RB][b][kc*32 + lg*8]; \
    f32x4 acc[4]; \
    _Pragma("unroll") for (int q=0;q<4;++q) acc[q]=fz4(); \
    _Pragma("unroll") for (int kc=0;kc<4;++kc) \
      _Pragma("unroll") for (int q=0;q<4;++q) acc[q] = MFMA(wf[q][kc], hf[kc], acc[q]); \
    float gv0[4], gv1[4]; \
    _Pragma("unroll") for (int q=0;q<4;++q){ \
      f32x4 v = acc[q]; \
      gv0[q] = (half ? v[2] : v[0]) + gq[q*2]; \
      gv1[q] = (half ? v[3] : v[1]) + gq[q*2+1]; } \
    float i0=sigm(gv0[0]), f0=sigm(gv0[1]), t0=tanhx(gv0[2]), o0=sigm(gv0[3]); \
    cs0 = f0*cs0 + i0*t0; float h0 = o0*tanhx(cs0); hs0 += h0; \
    float i1=sigm(gv1[0]), f1=sigm(gv1[1]), t1=tanhx(gv1[2]), o1=sigm(gv1[3]); \
    cs1 = f1*cs1 + i1*t1; float h1 = o1*tanhx(cs1); hs1 += h1; \
    *(unsigned*)&hbuf[WB][b][j0] = pk2(h0,h1); \
    __syncthreads(); }

  for (int it=0; it<512; ++it){
    LSTM_STEP(0, 1, gA)
    LSTM_STEP(1, 0, gB)
  }
#undef LSTM_STEP
  lc[b*256 + dir*128 + j0]     = hs0*(1.f/1024.f);
  lc[b*256 + dir*128 + j0 + 1] = hs1*(1.f/1024.f);
}

// ---------------- MHA: two-sweep softmax column weights ----------------
template<int MODE>
__global__ __launch_bounds__(256,1) void k_mha(const float* __restrict__ qkv, float* __restrict__ rowsum,
                                               float* __restrict__ colw){
  int rb = blockIdx.x, h2 = blockIdx.y, b = blockIdx.z;
  __shared__ __bf16 Qs[256][136];
  __shared__ __bf16 Ks[128][136];
  int tid=threadIdx.x, l=tid&63, w=tid>>6, lr=l&15, lg=l>>4;
  {
    const float qs = LOG2E / sqrtf(128.0f);
    int row = tid;
    const float* p = qkv + ((size_t)(b*1024 + rb*256 + row))*1536 + h2*128;
    #pragma unroll
    for (int cc=0; cc<128; cc+=8){
      f32x4 u0 = *(const f32x4*)(p+cc), u1 = *(const f32x4*)(p+cc+4);
      bf16x8 v;
      #pragma unroll
      for (int j=0;j<4;++j){ v[j]=(__bf16)(u0[j]*qs); v[j+4]=(__bf16)(u1[j]*qs); }
      *(bf16x8*)&Qs[row][cc] = v;
    }
  }
  float rs[4][4];
  if (MODE==1){
    #pragma unroll
    for (int mf=0;mf<4;++mf){ rs[mf][0]=0.f; rs[mf][1]=0.f; rs[mf][2]=0.f; rs[mf][3]=0.f; }
  } else {
    #pragma unroll
    for (int mf=0;mf<4;++mf)
      #pragma unroll
      for (int r=0;r<4;++r)
        rs[mf][r] = 1.0f / rowsum[((size_t)(b*4+h2))*1024 + rb*256 + w*64 + mf*16 + lg*4 + r];
  }
  for (int mc=0; mc<8; ++mc){
    __syncthreads();
    {
      int row = tid>>1, co = (tid&1)*64;
      const float* p = qkv + ((size_t)(b*1024 + mc*128 + row))*1536 + 512 + h2*128 + co;
      #pragma unroll
      for (int cc=0; cc<64; cc+=8){
        f32x4 u0 = *(const f32x4*)(p+cc), u1 = *(const f32x4*)(p+cc+4);
        bf16x8 v;
        #pragma unroll
        for (int j=0;j<4;++j){ v[j]=(__bf16)u0[j]; v[j+4]=(__bf16)u1[j]; }
        *(bf16x8*)&Ks[row][co+cc] = v;
      }
    }
    __syncthreads();
    f32x4 acc[4][8];
    #pragma unroll
    for (int mf=0;mf<4;++mf)
      #pragma unroll
      for (int nf=0;nf<8;++nf) acc[mf][nf]=fz4();
    #pragma unroll
    for (int ks=0;ks<4;++ks){
      bf16x8 aF[4], bFv[8];
      #pragma unroll
      for (int mf=0;mf<4;++mf) aF[mf] = *(const bf16x8*)&Qs[w*64+mf*16+lr][ks*32+lg*8];
      #pragma unroll
      for (int nf=0;nf<8;++nf) bFv[nf] = *(const bf16x8*)&Ks[nf*16+lr][ks*32+lg*8];
      #pragma unroll
      for (int mf=0;mf<4;++mf)
        #pragma unroll
        for (int nf=0;nf<8;++nf) acc[mf][nf] = MFMA(aF[mf], bFv[nf], acc[mf][nf]);
    }
    if (MODE==1){
      #pragma unroll
      for (int mf=0;mf<4;++mf)
        #pragma unroll
        for (int nf=0;nf<8;++nf)
          #pragma unroll
          for (int r=0;r<4;++r) rs[mf][r] += exp2f(acc[mf][nf][r]);
    } else {
      #pragma unroll
      for (int nf=0;nf<8;++nf){
        float cv = 0.f;
        #pragma unroll
        for (int mf=0;mf<4;++mf)
          #pragma unroll
          for (int r=0;r<4;++r) cv += exp2f(acc[mf][nf][r])*rs[mf][r];
        cv += __shfl_xor(cv,16);
        cv += __shfl_xor(cv,32);
        if (lg==0)
          colw[(((size_t)(rb*4+w)*8 + b)*4 + h2)*1024 + mc*128 + nf*16 + lr] = cv;
      }
    }
  }
  if (MODE==1){
    #pragma unroll
    for (int mf=0;mf<4;++mf)
      #pragma unroll
      for (int r=0;r<4;++r){
        float v = rs[mf][r];
        v += __shfl_xor(v,1); v += __shfl_xor(v,2); v += __shfl_xor(v,4); v += __shfl_xor(v,8);
        if (lr==0) rowsum[((size_t)(b*4+h2))*1024 + rb*256 + w*64 + mf*16 + lg*4 + r] = v;
      }
  }
}

__global__ void k_mha3(const float* __restrict__ qkv, const float* __restrict__ colw, float* __restrict__ acm){
  int h2 = blockIdx.x & 3, b = blockIdx.x >> 2;
  int tid = threadIdx.x;
  __shared__ float cwred[1024];
  for (int m=tid; m<1024; m+=256){
    float cw=0.f;
    #pragma unroll
    for (int t16=0;t16<16;++t16) cw += colw[(((size_t)t16*8 + b)*4 + h2)*1024 + m];
    cwred[m]=cw;
  }
  __syncthreads();
  int e = tid & 127, half = tid >> 7;
  float s = 0.f;
  for (int m = half*512; m < half*512+512; ++m)
    s += cwred[m] * qkv[((size_t)(b*1024+m))*1536 + 1024 + h2*128 + e];
  __shared__ float red[256];
  red[tid]=s; __syncthreads();
  if (tid<128) acm[((size_t)(b*4+h2))*128 + e] = (red[tid]+red[tid+128])*(1.f/1024.f);
}

__global__ void k_xmean(const float* __restrict__ x, float* __restrict__ xmean){
  int b = blockIdx.x, c = threadIdx.x; // 512
  float s=0.f;
  for (int n=0;n<1024;++n) s += x[((size_t)(b*1024+n))*512 + c];
  xmean[b*512+c] = s*(1.f/1024.f);
}

__global__ __launch_bounds__(256) void k_coeffs(float* __restrict__ ws,
                        const float* __restrict__ mow, const float* __restrict__ mob,
                        const float* __restrict__ ca_w1, const float* __restrict__ ca_b1,
                        const float* __restrict__ ca_w2, const float* __restrict__ ca_b2){
  int b = blockIdx.x, tid = threadIdx.x;
  __shared__ float av[512], comb[512], hid[256];
  for (int i=tid;i<512;i+=256) av[i] = ws[OFF_ACM + b*512 + i];
  __syncthreads();
  for (int c=tid;c<512;c+=256){
    float s = mob[c];
    for (int k=0;k<512;++k) s += mow[(size_t)c*512+k]*av[k];
    comb[c] = s + ws[OFF_XMEAN + b*512 + c] + ((c<256) ? ws[OFF_LC + b*256 + c] : 0.f);
  }
  __syncthreads();
  for (int j=tid;j<256;j+=256){
    float s = ca_b1[j];
    for (int k=0;k<512;++k) s += ca_w1[(size_t)j*512+k]*comb[k];
    hid[j] = fmaxf(s,0.f);
  }
  __syncthreads();
  if (tid<32){
    float s = ca_b2[tid];
    for (int k=0;k<256;++k) s += ca_w2[tid*256+k]*hid[k];
    ws[OFF_COEF + b*32 + tid] = 1.f/(1.f+expf(-s));
  }
}

// ---------------- spectral: forward DFT + filter -> Hb ----------------
__global__ __launch_bounds__(256,2) void k_spec1(const float* __restrict__ qkv, float* __restrict__ ws){
  int qk = blockIdx.x, h = blockIdx.y, b = blockIdx.z;
  int colbase = qk*512 + h*64;
  int tid=threadIdx.x, l=tid&63, w=tid>>6, lr=l&15, lg=l>>4;
  __shared__ __bf16 tT[64][520];
  __shared__ float M1[32][64];
  __shared__ float G2[256][2];
  const __bf16* w1cs = (const __bf16*)(ws + OFF_W1CS);
  f32x4 acc[2]; acc[0]=fz4(); acc[1]=fz4();
  for (int c0=0; c0<2; ++c0){
    __syncthreads();
    {
      int p = tid;
      int m0 = c0*512 + 2*p;
      const float* r0 = qkv + ((size_t)(b*1024 + m0))*1536 + colbase;
      const float* r1 = r0 + 1536;
      #pragma unroll
      for (int e=0;e<64;e+=4){
        f32x4 u0 = *(const f32x4*)(r0+e);
        f32x4 u1 = *(const f32x4*)(r1+e);
        #pragma unroll
        for (int j=0;j<4;++j) *(unsigned*)&tT[e+j][2*p] = pk2(u0[j], u1[j]);
      }
    }
    __syncthreads();
    for (int ks=0; ks<16; ++ks){
      bf16x8 bf = *(const bf16x8*)&tT[w*16+lr][ks*32+lg*8];
      #pragma unroll
      for (int mf=0;mf<2;++mf){
        bf16x8 af = *(const bf16x8*)(w1cs + (size_t)(mf*16+lr)*1024 + c0*512 + ks*32 + lg*8);
        acc[mf] = MFMA(af, bf, acc[mf]);
      }
    }
  }
  #pragma unroll
  for (int mf=0;mf<2;++mf)
    #pragma unroll
    for (int r=0;r<4;++r) M1[mf*16 + lg*4 + r][w*16 + lr] = acc[mf][r];
  __syncthreads();
  {
    int k1 = tid>>4, k2 = tid&15;
    float tfr=0.f, tfi=0.f;
    const float* w2 = ws + OFF_W2;
    for (int e=0;e<64;++e){
      float mr = M1[k1][e], mi = M1[16+k1][e];
      float cr = w2[(e*16+k2)*2], ci = w2[(e*16+k2)*2+1];
      tfr += mr*cr - mi*ci;
      tfi += mr*ci + mi*cr;
    }
    float wr = ws[OFF_WEFF + ((size_t)h*256 + k1*16 + k2)*2];
    float wi = ws[OFF_WEFF + ((size_t)h*256 + k1*16 + k2)*2 + 1];
    G2[tid][0] = tfr*wr - tfi*wi;
    G2[tid][1] = tfr*wi + tfi*wr;
  }
  __syncthreads();
  __bf16* hb = (__bf16*)(ws + OFF_HB) + ((size_t)((b*8+h)*2+qk))*2048;
  const float* w2 = ws + OFF_W2;
  for (int f=tid; f<1024; f+=256){
    int k1 = f>>6, d = f&63;
    float hr=0.f, hi=0.f;
    #pragma unroll
    for (int k2=0;k2<16;++k2){
      float gr=G2[k1*16+k2][0], gi=G2[k1*16+k2][1];
      float sc = k2 ? 2.f : 1.f;
      float cr = sc*w2[(d*16+k2)*2];
      float ci = -sc*w2[(d*16+k2)*2+1];
      hr += gr*cr - gi*ci;
      hi += gr*ci + gi*cr;
    }
    const float inv = 1.0f/65536.0f;
    hb[d*32 + k1]      = (__bf16)(hr*inv);
    hb[d*32 + 16 + k1] = (__bf16)(-hi*inv);
  }
}

// ---------------- spectral: inverse DFT apply (overwrite q/k) ----------------
__global__ __launch_bounds__(256,2) void k_spec2(float* __restrict__ qkv, const float* __restrict__ ws){
  int qk=blockIdx.x, h=blockIdx.y, b=blockIdx.z;
  int colbase = qk*512 + h*64;
  int tid=threadIdx.x, l=tid&63, w=tid>>6, lr=l&15, lg=l>>4;
  __shared__ __bf16 hbl[2048];
  const __bf16* hb = (const __bf16*)(ws + OFF_HB) + ((size_t)((b*8+h)*2+qk))*2048;
  *(bf16x8*)&hbl[tid*8] = *(const bf16x8*)&hb[tid*8];
  __syncthreads();
  const __bf16* w1t = (const __bf16*)(ws + OFF_W1T);
  bf16x8 bF[4];
  #pragma unroll
  for (int nf=0;nf<4;++nf) bF[nf] = *(const bf16x8*)&hbl[(nf*16+lr)*32 + lg*8];
  for (int pass=0; pass<4; ++pass){
    int rowbase = w*256 + pass*64;
    f32x4 acc[4][4];
    #pragma unroll
    for (int mf=0;mf<4;++mf){ acc[mf][0]=fz4(); acc[mf][1]=fz4(); acc[mf][2]=fz4(); acc[mf][3]=fz4(); }
    #pragma unroll
    for (int mf=0;mf<4;++mf){
      bf16x8 aF = *(const bf16x8*)(w1t + (size_t)(rowbase+mf*16+lr)*32 + lg*8);
      #pragma unroll
      for (int nf=0;nf<4;++nf) acc[mf][nf] = MFMA(aF, bF[nf], acc[mf][nf]);
    }
    #pragma unroll
    for (int mf=0;mf<4;++mf)
      #pragma unroll
      for (int nf=0;nf<4;++nf)
        #pragma unroll
        for (int r=0;r<4;++r){
          int n = rowbase + mf*16 + lg*4 + r;
          int d = nf*16 + lr;
          qkv[((size_t)(b*1024+n))*1536 + colbase + d] = acc[mf][nf][r];
        }
  }
}

// ---------------- polarity linear attention ----------------
__global__ __launch_bounds__(256,1) void k_polar(const float* __restrict__ qkv, const float* __restrict__ ws,
                                                 float* __restrict__ accum, int s){
  int h = blockIdx.x, b = blockIdx.y;
  int tid=threadIdx.x, l=tid&63, w=tid>>6, lr=l&15, lg=l>>4;
  __shared__ float plds[23200];
  __bf16* kpT = (__bf16*)plds;
  __bf16* knT = (__bf16*)((char*)plds + 17408);
  __bf16* vT  = (__bf16*)((char*)plds + 34816);
  float* scal = (float*)((char*)plds + 92416);
  float* pvs  = scal + 8;
  if (tid<4)  scal[tid] = ws[OFF_COEF + b*32 + h*4 + tid];
  if (tid==4) scal[4] = ws[OFF_GMIX + 2*h];
  if (tid==5) scal[5] = ws[OFF_GMIX + 2*h+1];
  if (tid<64) pvs[tid] = ws[OFF_PPOW + ((size_t)s*8+h)*64 + tid];
  for (int i=tid; i<16*136; i+=256) vT[64*136 + i] = (__bf16)((i<136)?1.0f:0.0f);
  f32x4 acc[4][5];
  #pragma unroll
  for (int mf=0;mf<4;++mf)
    #pragma unroll
    for (int nf=0;nf<5;++nf) acc[mf][nf]=fz4();
  for (int mc=0;mc<8;++mc){
    __syncthreads();
    #pragma unroll
    for (int it=0; it<16; ++it){
      int flat = tid + 256*it;
      int d = flat & 63, np = flat >> 6;
      int n = mc*128 + 2*np;
      const float* kr = qkv + ((size_t)(b*1024+n))*1536 + 512 + h*64 + d;
      const float* vr = qkv + ((size_t)(b*1024+n))*1536 + 1024 + h*64 + d;
      float p = pvs[d];
      float k0=kr[0], k1=kr[1536], v0=vr[0], v1=vr[1536];
      float kp0,kn0,kp1,kn1;
      powpair(k0,p,kp0,kn0); powpair(k1,p,kp1,kn1);
      *(unsigned*)&kpT[d*136 + 2*np] = pk2(kp0,kp1);
      *(unsigned*)&knT[d*136 + 2*np] = pk2(kn0,kn1);
      *(unsigned*)&vT [d*136 + 2*np] = pk2(v0,v1);
    }
    __syncthreads();
    const __bf16* A = (w&2)?knT:kpT;
    int kh = (w&1)*64;
    #pragma unroll
    for (int ks=0;ks<2;++ks){
      bf16x8 aF[4];
      #pragma unroll
      for (int mf=0;mf<4;++mf) aF[mf] = *(const bf16x8*)&A[(mf*16+lr)*136 + kh + ks*32 + lg*8];
      #pragma unroll
      for (int nf=0;nf<5;++nf){
        bf16x8 bFv = *(const bf16x8*)&vT[(nf*16+lr)*136 + kh + ks*32 + lg*8];
        #pragma unroll
        for (int mf=0;mf<4;++mf) acc[mf][nf] = MFMA(aF[mf], bFv, acc[mf][nf]);
      }
    }
  }
  __syncthreads();
  float* kvf = plds; // [2][64][80]
  if ((w&1)==0){
    int mat = w>>1;
    #pragma unroll
    for (int mf=0;mf<4;++mf)
      #pragma unroll
      for (int nf=0;nf<5;++nf)
        #pragma unroll
        for (int r=0;r<4;++r)
          kvf[((size_t)mat*64 + mf*16+lg*4+r)*80 + nf*16+lr] = acc[mf][nf][r];
  }
  __syncthreads();
  if (w&1){
    int mat = w>>1;
    #pragma unroll
    for (int mf=0;mf<4;++mf)
      #pragma unroll
      for (int nf=0;nf<5;++nf)
        #pragma unroll
        for (int r=0;r<4;++r)
          kvf[((size_t)mat*64 + mf*16+lg*4+r)*80 + nf*16+lr] += acc[mf][nf][r];
  }
  __syncthreads();
  __bf16* Bm = (__bf16*)((char*)plds + 69632);
  {
    float c0=scal[0], c1=scal[1], c2=scal[2], c3=scal[3], g0=scal[4], g1=scal[5];
    for (int f=tid; f<80*128; f+=256){
      int e=f>>7, kk=f&127;
      float v;
      if (e<64){
        if (kk<64) v = g0*c0*kvf[kk*80+e] + g1*c2*kvf[(64+kk)*80+e];
        else { int k2=kk-64; v = g0*c1*kvf[(64+k2)*80+e] + g1*c3*kvf[k2*80+e]; }
      } else if (e==64){
        v = (kk<64) ? kvf[kk*80+64] : kvf[(64+(kk-64))*80+64];
      } else v = 0.f;
      Bm[e*136+kk] = (__bf16)v;
    }
  }
  __syncthreads();
  bf16x8 bF2[5][4];
  #pragma unroll
  for (int nf=0;nf<5;++nf)
    #pragma unroll
    for (int ks=0;ks<4;++ks) bF2[nf][ks] = *(const bf16x8*)&Bm[(nf*16+lr)*136 + ks*32 + lg*8];
  __bf16* At = (__bf16*)plds;
  float* zb = (float*)((char*)plds + 91392);
  for (int pass=0; pass<4; ++pass){
    __syncthreads();
    #pragma unroll
    for (int it=0; it<16; ++it){
      int flat = tid + 256*it;
      int row = flat>>4, dg = flat&15;
      int n = pass*256 + row;
      const float* qr = qkv + ((size_t)(b*1024+n))*1536 + h*64 + dg*4;
      f32x4 u = *(const f32x4*)qr;
      float qp[4], qn[4];
      #pragma unroll
      for (int j=0;j<4;++j) powpair(u[j], pvs[dg*4+j], qp[j], qn[j]);
      *(unsigned*)&At[row*136 + dg*4]        = pk2(qp[0],qp[1]);
      *(unsigned*)&At[row*136 + dg*4+2]      = pk2(qp[2],qp[3]);
      *(unsigned*)&At[row*136 + 64 + dg*4]   = pk2(qn[0],qn[1]);
      *(unsigned*)&At[row*136 + 64 + dg*4+2] = pk2(qn[2],qn[3]);
    }
    __syncthreads();
    f32x4 a2[4][5];
    #pragma unroll
    for (int mf=0;mf<4;++mf)
      #pragma unroll
      for (int nf=0;nf<5;++nf) a2[mf][nf]=fz4();
    #pragma unroll
    for (int ks=0;ks<4;++ks){
      bf16x8 aF[4];
      #pragma unroll
      for (int mf=0;mf<4;++mf) aF[mf] = *(const bf16x8*)&At[(w*64+mf*16+lr)*136 + ks*32 + lg*8];
      #pragma unroll
      for (int nf=0;nf<5;++nf)
        #pragma unroll
        for (int mf=0;mf<4;++mf) a2[mf][nf] = MFMA(aF[mf], bF2[nf][ks], a2[mf][nf]);
    }
    if (lr==0){
      #pragma unroll
      for (int mf=0;mf<4;++mf)
        #pragma unroll
        for (int r=0;r<4;++r) zb[w*64 + mf*16 + lg*4 + r] = a2[mf][4][r] + 1e-6f;
    }
    __syncthreads();
    #pragma unroll
    for (int mf=0;mf<4;++mf){
      float rz[4];
      #pragma unroll
      for (int r=0;r<4;++r) rz[r] = 1.0f / zb[w*64 + mf*16 + lg*4 + r];
      #pragma unroll
      for (int nf=0;nf<4;++nf)
        #pragma unroll
        for (int r=0;r<4;++r){
          int n = pass*256 + w*64 + mf*16 + lg*4 + r;
          int e = nf*16 + lr;
          size_t oi = ((size_t)((b*8+h)*1024) + n)*64 + e;
          float v = a2[mf][nf][r]*rz[r];
          if (s==0) accum[oi] = v; else accum[oi] += v;
        }
    }
  }
}

// ---------------- combined 9x9 depthwise conv ----------------
__global__ __launch_bounds__(256,2) void k_conv(const float* __restrict__ qkv, const float* __restrict__ ws,
                                                float* __restrict__ accum){
  int bid = blockIdx.x;
  int sl = bid & 3, h = (bid>>2)&7, b = bid>>5;
  int tid = threadIdx.x;
  __shared__ float vs[1024][16];
  __shared__ float wc[16][81];
  __shared__ float cb[16];
  for (int it=0; it<64; ++it){
    int flat = tid + 256*it;
    int c = flat & 15, pix = flat>>4;
    vs[pix][c] = qkv[((size_t)(b*1024+pix))*1536 + 1024 + h*64 + sl*16 + c];
  }
  for (int f=tid; f<16*81; f+=256) wc[f/81][f%81] = ws[OFF_CONV9 + (size_t)(sl*16 + f/81)*81 + (f%81)];
  if (tid<16) cb[tid] = ws[OFF_CBIAS + sl*16 + tid];
  __syncthreads();
  #pragma unroll
  for (int cc=0; cc<2; ++cc){
    int col = tid + 256*cc;
    int c = col & 15, x = col >> 4;
    float a[32];
    #pragma unroll
    for (int y=0;y<32;++y) a[y]=0.f;
    #pragma unroll
    for (int dx=-4; dx<=4; ++dx){
      int xx = x+dx;
      bool xv = (xx>=0)&&(xx<32);
      float colv[40];
      #pragma unroll
      for (int i=0;i<40;++i){
        int yy = i-4;
        colv[i] = (xv && yy>=0 && yy<32) ? vs[yy*32+xx][c] : 0.f;
      }
      #pragma unroll
      for (int dy=0; dy<9; ++dy){
        float wv = wc[c][dy*9 + dx+4];
        #pragma unroll
        for (int y=0;y<32;++y) a[y] += wv*colv[y+dy];
      }
    }
    float bias = cb[c];
    #pragma unroll
    for (int y=0;y<32;++y){
      size_t oi = ((size_t)((b*8+h)*1024) + y*32 + x)*64 + sl*16 + c;
      accum[oi] += a[y] + bias;
    }
  }
}

__global__ void k_finalize(const float* __restrict__ accum, float* __restrict__ fin){
  int idx = blockIdx.x*256 + threadIdx.x;
  int c = idx & 511, n = (idx>>9)&1023, b = idx>>19;
  int h = c>>6, d = c&63;
  fin[idx] = accum[((size_t)((b*8+h)*1024)+n)*64 + d] * (1.0f/3.0f);
}

// ---------------- launch ----------------
extern "C" void kernel_launch(void* const* d_in, const int* in_sizes, int n_in,
                              void* d_out, int out_size, void* d_ws, size_t ws_size,
                              hipStream_t stream){
  const float* x        = (const float*)d_in[0];
  const float* qkv_w    = (const float*)d_in[3];
  const float* proj_w   = (const float*)d_in[4];
  const float* proj_b   = (const float*)d_in[5];
  const float* pos_sw   = (const float*)d_in[6];
  const float* neg_sw   = (const float*)d_in[7];
  const float* ca_w1    = (const float*)d_in[9];
  const float* ca_b1    = (const float*)d_in[10];
  const float* ca_w2    = (const float*)d_in[11];
  const float* ca_b2    = (const float*)d_in[12];
  const float* wih_f    = (const float*)d_in[13];
  const float* whh_f    = (const float*)d_in[14];
  const float* bih_f    = (const float*)d_in[15];
  const float* bhh_f    = (const float*)d_in[16];
  const float* wih_b    = (const float*)d_in[17];
  const float* whh_b    = (const float*)d_in[18];
  const float* bih_b    = (const float*)d_in[19];
  const float* bhh_b    = (const float*)d_in[20];
  const float* mha_in_w = (const float*)d_in[21];
  const float* mha_in_b = (const float*)d_in[22];
  const float* mha_out_w= (const float*)d_in[23];
  const float* mha_out_b= (const float*)d_in[24];
  const float* ge_b1    = (const float*)d_in[26];
  const float* ge_w2    = (const float*)d_in[27];
  const float* ge_b2    = (const float*)d_in[28];
  const float* spw      = (const float*)d_in[29];
  const float* w5 = (const float*)d_in[30]; const float* b5 = (const float*)d_in[31];
  const float* w7 = (const float*)d_in[32]; const float* b7 = (const float*)d_in[33];
  const float* w9 = (const float*)d_in[34]; const float* b9 = (const float*)d_in[35];
  const float* mode_w = (const float*)d_in[36];
  float* ws  = (float*)d_ws;
  float* out = (float*)d_out;

  k_const<<<1,256,0,stream>>>(ge_b1, ge_w2, ge_b2, mode_w, w5,b5,w7,b7,w9,b9,
                              pos_sw, neg_sw, spw, bih_f,bhh_f,bih_b,bhh_b, ws);
  // LSTM input gemms (gates in (b,t,512)) -> transpose -> scan
  k_gemm<<<dim3(4,64),256,0,stream>>>(x, wih_f, ws+OFF_LBIAS,     ws+OFF_R0,          8192,512,512);
  k_gemm<<<dim3(4,64),256,0,stream>>>(x, wih_b, ws+OFF_LBIAS+512, ws+OFF_R0+4194304,  8192,512,512);
  k_gxt<<<2048,256,0,stream>>>(ws+OFF_R0, ws+OFF_GXT);
  k_lstm_scan<<<2,512,0,stream>>>(whh_f, whh_b, ws+OFF_GXT, ws+OFF_LC);
  // MHA branch
  k_gemm<<<dim3(12,64),256,0,stream>>>(x, mha_in_w, mha_in_b, ws+OFF_R0, 8192,1536,512);
  k_mha<1><<<dim3(4,4,8),256,0,stream>>>(ws+OFF_R0, ws+OFF_ROWSUM, ws+OFF_COLW);
  k_mha<2><<<dim3(4,4,8),256,0,stream>>>(ws+OFF_R0, ws+OFF_ROWSUM, ws+OFF_COLW);
  k_mha3<<<32,256,0,stream>>>(ws+OFF_R0, ws+OFF_COLW, ws+OFF_ACM);
  k_xmean<<<8,512,0,stream>>>(x, ws+OFF_XMEAN);
  k_coeffs<<<8,256,0,stream>>>(ws, mha_out_w, mha_out_b, ca_w1, ca_b1, ca_w2, ca_b2);
  // scales
  for (int s=0; s<3; ++s){
    k_gemm<<<dim3(12,64),256,0,stream>>>(x, qkv_w + (size_t)s*1536*512, nullptr, ws+OFF_R0, 8192,1536,512);
    k_spec1<<<dim3(2,8,8),256,0,stream>>>(ws+OFF_R0, ws);
    k_spec2<<<dim3(2,8,8),256,0,stream>>>(ws+OFF_R0, ws);
    k_polar<<<dim3(8,8),256,0,stream>>>(ws+OFF_R0, ws, ws+OFF_ACCUM, s);
    k_conv<<<256,256,0,stream>>>(ws+OFF_R0, ws, ws+OFF_ACCUM);
  }
  k_finalize<<<16384,256,0,stream>>>(ws+OFF_ACCUM, ws+OFF_FINAL);
  k_gemm<<<dim3(4,64),256,0,stream>>>(ws+OFF_FINAL, proj_w, proj_b, out, 8192,512,512);
}

// Round 5
// 1981.639 us; speedup vs baseline: 1.7654x; 1.2325x over previous
//
#include <hip/hip_runtime.h>
#include <hip/hip_bf16.h>
#include <math.h>

typedef __bf16 bf16x8 __attribute__((ext_vector_type(8)));
typedef float  f32x4  __attribute__((ext_vector_type(4)));

#define MFMA(a,b,c) __builtin_amdgcn_mfma_f32_16x16x32_bf16(a, b, c, 0, 0, 0)
#define LOG2E 1.4426950408889634f

// ---------------- workspace float offsets ----------------
static constexpr size_t OFF_R0    = 0;                       // 12,582,912 : gates(f,b) then qkv buffer
static constexpr size_t OFF_GXT   = 12582912;                // 8,388,608 : gxt -> later accum+final
static constexpr size_t OFF_ACCUM = OFF_GXT;                 // 4,194,304
static constexpr size_t OFF_FINAL = OFF_GXT + 4194304;       // 4,194,304
static constexpr size_t SOFF      = OFF_GXT + 8388608;
static constexpr size_t OFF_ROWSUM= SOFF;                    // 32768
static constexpr size_t OFF_COLW  = OFF_ROWSUM + 32768;      // 524288 (16 deterministic partials)
static constexpr size_t OFF_ACM   = OFF_COLW + 524288;       // 4096
static constexpr size_t OFF_XMEAN = OFF_ACM + 4096;          // 4096
static constexpr size_t OFF_LC    = OFF_XMEAN + 4096;        // 2048
static constexpr size_t OFF_COEF  = OFF_LC + 2048;           // 256
static constexpr size_t OFF_GMIX  = OFF_COEF + 256;          // 16
static constexpr size_t OFF_MW    = OFF_GMIX + 16;           // 4
static constexpr size_t OFF_CONV9 = OFF_MW + 4;              // 5184
static constexpr size_t OFF_CBIAS = OFF_CONV9 + 5184;        // 64
static constexpr size_t OFF_WEFF  = OFF_CBIAS + 64;          // 4096 (8*16*16 complex)
static constexpr size_t OFF_PPOW  = OFF_WEFF + 4096;         // 1536
static constexpr size_t OFF_LBIAS = OFF_PPOW + 1536;         // 1024
static constexpr size_t OFF_W2    = OFF_LBIAS + 1024;        // 2048 (64*16 complex, e^{-i})
static constexpr size_t OFF_W1CS  = OFF_W2 + 2048;           // 16384 floats = bf16[32][1024]
static constexpr size_t OFF_W1T   = OFF_W1CS + 16384;        // 16384 floats = bf16[1024][32]
static constexpr size_t OFF_HB    = OFF_W1T + 16384;         // 131072 floats = bf16[128][2048]

__device__ __forceinline__ float sigm(float x){ return __builtin_amdgcn_rcpf(1.0f + exp2f(-LOG2E*x)); }
__device__ __forceinline__ float tanhx(float x){ return 2.0f*__builtin_amdgcn_rcpf(1.0f + exp2f(-2.0f*LOG2E*x)) - 1.0f; }
__device__ __forceinline__ unsigned pk2(float a, float b){
  union { __bf16 h[2]; unsigned u; } z; z.h[0]=(__bf16)a; z.h[1]=(__bf16)b; return z.u;
}
__device__ __forceinline__ void powpair(float t, float p, float& pos, float& neg){
  float a = fabsf(t);
  float v = (a > 0.f) ? exp2f(p * __log2f(a)) : 0.f;
  pos = (t > 0.f) ? v : 0.f;
  neg = (t < 0.f) ? v : 0.f;
}
__device__ __forceinline__ f32x4 fz4(){ return (f32x4){0.f,0.f,0.f,0.f}; }

// ---------------- constants / tables ----------------
__global__ void k_const(const float* __restrict__ ge_b1, const float* __restrict__ ge_w2,
                        const float* __restrict__ ge_b2, const float* __restrict__ mode_w,
                        const float* __restrict__ w5, const float* __restrict__ b5,
                        const float* __restrict__ w7, const float* __restrict__ b7,
                        const float* __restrict__ w9, const float* __restrict__ b9,
                        const float* __restrict__ pos_sw, const float* __restrict__ neg_sw,
                        const float* __restrict__ spw,
                        const float* __restrict__ bih_f, const float* __restrict__ bhh_f,
                        const float* __restrict__ bih_b, const float* __restrict__ bhh_b,
                        float* __restrict__ ws){
  int tid = threadIdx.x; // 256
  __shared__ float mw[3];
  __shared__ float tgh[256];
  __shared__ float sbuf[16];
  tgh[tid] = tanhf(ge_b1[tid]);
  if (tid == 0){
    float m0=mode_w[0], m1=mode_w[1], m2=mode_w[2];
    float mx = fmaxf(m0, fmaxf(m1,m2));
    float e0=expf(m0-mx), e1=expf(m1-mx), e2=expf(m2-mx);
    float s = e0+e1+e2;
    mw[0]=e0/s; mw[1]=e1/s; mw[2]=e2/s;
    ws[OFF_MW+0]=mw[0]; ws[OFF_MW+1]=mw[1]; ws[OFF_MW+2]=mw[2];
  }
  __syncthreads();
  if (tid < 16){
    float s = ge_b2[tid];
    for (int i=0;i<256;++i) s += ge_w2[tid*256+i]*tgh[i];
    sbuf[tid] = s;
  }
  __syncthreads();
  if (tid < 8){
    float a = sbuf[2*tid], b = sbuf[2*tid+1];
    float m = fmaxf(a,b);
    float ea = expf(a-m), eb = expf(b-m);
    ws[OFF_GMIX+2*tid]   = ea/(ea+eb);
    ws[OFF_GMIX+2*tid+1] = eb/(ea+eb);
  }
  for (int j=tid;j<512;j+=256){
    ws[OFF_LBIAS+j]     = bih_f[j]+bhh_f[j];
    ws[OFF_LBIAS+512+j] = bih_b[j]+bhh_b[j];
  }
  for (int f=tid; f<5184; f+=256){
    int d=f/81, t=f%81, ky=t/9, kx=t%9, dy=ky-4, dx=kx-4;
    float v = mw[2]*w9[d*81+t];
    if (dy>=-3 && dy<=3 && dx>=-3 && dx<=3) v += mw[1]*w7[d*49 + (dy+3)*7 + (dx+3)];
    if (dy>=-2 && dy<=2 && dx>=-2 && dx<=2) v += mw[0]*w5[d*25 + (dy+2)*5 + (dx+2)];
    ws[OFF_CONV9+f] = v;
  }
  if (tid<64) ws[OFF_CBIAS+tid] = mw[0]*b5[tid]+mw[1]*b7[tid]+mw[2]*b9[tid];
  // w_eff = wp + (1/16) wn   (softmax(spec_mix).mean(-1) == 1/16 exactly)
  for (int f=tid; f<2048; f+=256){
    int h=f>>8, k1=(f>>4)&15, k2=f&15;
    int src = ((h*16+k1)*64 + k2)*2;
    ws[OFF_WEFF+2*f]   = pos_sw[src]   + 0.0625f*neg_sw[src];
    ws[OFF_WEFF+2*f+1] = pos_sw[src+1] + 0.0625f*neg_sw[src+1];
  }
  for (int f=tid; f<1536; f+=256) ws[OFF_PPOW+f] = 1.0f + fabsf(spw[f]);
  // W2 (64x16 complex e^{-i 2pi e k2/64})
  for (int f=tid; f<1024; f+=256){
    int e=f>>4, k2=f&15; int ph=(e*k2)&63;
    float th = (float)ph * (6.283185307179586f/64.0f);
    ws[OFF_W2+2*f]   = cosf(th);
    ws[OFF_W2+2*f+1] = -sinf(th);
  }
  // W1CS bf16 [32][1024]: rows 0..15 cos, rows 16..31 -sin  (forward DFT)
  __bf16* w1cs = (__bf16*)(ws + OFF_W1CS);
  for (int f=tid; f<32768; f+=256){
    int r=f>>10, m=f&1023; int k1=r&15; int ph=(k1*m)&1023;
    float th = (float)ph * (6.283185307179586f/1024.0f);
    w1cs[f] = (__bf16)((r<16)?cosf(th):-sinf(th));
  }
  // W1T bf16 [1024][32]: cols 0..15 cos, cols 16..31 +sin (inverse DFT)
  __bf16* w1t = (__bf16*)(ws + OFF_W1T);
  for (int f=tid; f<32768; f+=256){
    int n=f>>5, r=f&31; int k1=r&15; int ph=(k1*n)&1023;
    float th = (float)ph * (6.283185307179586f/1024.0f);
    w1t[f] = (__bf16)((r<16)?cosf(th):sinf(th));
  }
}

// ---------------- generic GEMM: C[M,N] = A[M,K] @ W[N,K]^T (+bias), fp32 io, bf16 mfma ----------------
__global__ __launch_bounds__(256,2) void k_gemm(const float* __restrict__ A, const float* __restrict__ W,
                                                const float* __restrict__ bias, float* __restrict__ C,
                                                int M, int N, int K){
  __shared__ __bf16 As[128][40];
  __shared__ __bf16 Ws[128][40];
  int tid = threadIdx.x;
  int n0 = blockIdx.x * 128, m0 = blockIdx.y * 128;
  int l = tid & 63, wid = tid >> 6, lr = l & 15, lg = l >> 4;
  int wr = wid >> 1, wc = wid & 1;
  f32x4 acc[4][4];
  #pragma unroll
  for (int i=0;i<4;++i){ acc[i][0]=fz4(); acc[i][1]=fz4(); acc[i][2]=fz4(); acc[i][3]=fz4(); }
  int srow = tid >> 1, sk = (tid & 1) * 16;
  const float* Ap = A + (size_t)(m0 + srow) * K + sk;
  const float* Wp = W + (size_t)(n0 + srow) * K + sk;
  for (int k0 = 0; k0 < K; k0 += 32){
    f32x4 a0=*(const f32x4*)(Ap), a1=*(const f32x4*)(Ap+4), a2=*(const f32x4*)(Ap+8), a3=*(const f32x4*)(Ap+12);
    f32x4 w0=*(const f32x4*)(Wp), w1=*(const f32x4*)(Wp+4), w2=*(const f32x4*)(Wp+8), w3=*(const f32x4*)(Wp+12);
    Ap += 32; Wp += 32;
    __syncthreads();
    bf16x8 va, vb, wa, wb;
    #pragma unroll
    for (int j=0;j<4;++j){ va[j]=(__bf16)a0[j]; va[j+4]=(__bf16)a1[j]; vb[j]=(__bf16)a2[j]; vb[j+4]=(__bf16)a3[j];
                           wa[j]=(__bf16)w0[j]; wa[j+4]=(__bf16)w1[j]; wb[j]=(__bf16)w2[j]; wb[j+4]=(__bf16)w3[j]; }
    *(bf16x8*)&As[srow][sk]   = va;  *(bf16x8*)&As[srow][sk+8] = vb;
    *(bf16x8*)&Ws[srow][sk]   = wa;  *(bf16x8*)&Ws[srow][sk+8] = wb;
    __syncthreads();
    bf16x8 aF[4], bF[4];
    #pragma unroll
    for (int mf=0;mf<4;++mf) aF[mf] = *(const bf16x8*)&As[wr*64+mf*16+lr][lg*8];
    #pragma unroll
    for (int nf=0;nf<4;++nf) bF[nf] = *(const bf16x8*)&Ws[wc*64+nf*16+lr][lg*8];
    #pragma unroll
    for (int mf=0;mf<4;++mf)
      #pragma unroll
      for (int nf=0;nf<4;++nf) acc[mf][nf] = MFMA(aF[mf], bF[nf], acc[mf][nf]);
  }
  #pragma unroll
  for (int mf=0;mf<4;++mf)
    #pragma unroll
    for (int nf=0;nf<4;++nf){
      int row = m0 + wr*64 + mf*16 + lg*4;
      int col = n0 + wc*64 + nf*16 + lr;
      float bv = bias ? bias[col] : 0.f;
      #pragma unroll
      for (int r=0;r<4;++r) C[(size_t)(row+r)*N + col] = acc[mf][nf][r] + bv;
    }
}

// ---------------- transpose gates (b,t,j) -> (t,j,b) ----------------
__global__ void k_gxt(const float* __restrict__ gates, float* __restrict__ gxt){
  int t = blockIdx.x & 1023, dir = blockIdx.x >> 10;
  int tid = threadIdx.x;
  const float* g = gates + (size_t)dir*4194304;
  float* o = gxt + (size_t)dir*4194304 + (size_t)t*4096;
  for (int j=tid; j<512; j+=256){
    float vv[8];
    #pragma unroll
    for (int b=0;b<8;++b) vv[b] = g[((size_t)b*1024 + t)*512 + j];
    f32x4 u0 = {vv[0],vv[1],vv[2],vv[3]}, u1 = {vv[4],vv[5],vv[6],vv[7]};
    *(f32x4*)(o + (size_t)j*8)     = u0;
    *(f32x4*)(o + (size_t)j*8 + 4) = u1;
  }
}

// ---------------- LSTM scan v4: 4 blocks = 2 dir x 2 batch-groups, 1 h/lane, fast-rcp activations ----------------
// gxt layout: (dir, t, j(512), b(8)) f32.  h in LDS [2][4][132] bf16 (double-buffered).
__global__ __launch_bounds__(512,1) void k_lstm_scan(const float* __restrict__ whh_f,
                                                     const float* __restrict__ whh_b,
                                                     const float* __restrict__ gxt,
                                                     float* __restrict__ lc){
  int dir = blockIdx.x >> 1, bg = blockIdx.x & 1;
  const float* __restrict__ whh = dir ? whh_b : whh_f;
  const float* gx0 = gxt + (size_t)dir*4194304;
  int tid=threadIdx.x, w=tid>>6, l=tid&63;
  int lr=l&15, lg=l>>4;          // MFMA row-within-tile and k-group
  int b4 = l&3, rsel = (l>>2)&3; // batch column (duplicated over bits 2-3 of col), row select
  // Weight fragments: A[row = q*128 + w*16 + lr][k = kc*32 + lg*8 + e]
  bf16x8 wf[4][4];
  #pragma unroll
  for (int q=0;q<4;++q)
    #pragma unroll
    for (int kc=0;kc<4;++kc){
      const float* p = whh + (size_t)(q*128 + w*16 + lr)*128 + kc*32 + lg*8;
      bf16x8 v;
      #pragma unroll
      for (int j=0;j<8;++j) v[j]=(__bf16)p[j];
      wf[q][kc]=v;
    }
  __shared__ __bf16 hbuf[2][4][132];
  for (int i=tid; i<2*4*132; i+=512) ((__bf16*)hbuf)[i] = (__bf16)0.0f;
  int j0 = w*16 + lg*4 + rsel;          // this lane's h row (0..127)
  int joff = j0*8 + bg*4 + b4;          // gxt per-t offset
  const float* ptr = gx0 + (dir ? (size_t)1023*4096 : 0);
  long tstride = dir ? -4096 : 4096;
  float cs=0.f, hs=0.f;
  float gA[4], gB[4];
  #pragma unroll
  for (int q=0;q<4;++q) gA[q] = ptr[q*1024+joff];
  ptr += tstride;
  #pragma unroll
  for (int q=0;q<4;++q) gB[q] = ptr[q*1024+joff];
  ptr += tstride;
  __syncthreads();

#define LSTM_STEP(RB, WB, G) { \
    float gq[4]; \
    _Pragma("unroll") for (int q=0;q<4;++q) gq[q]=G[q]; \
    _Pragma("unroll") for (int q=0;q<4;++q) G[q]=ptr[q*1024+joff]; \
    ptr += tstride; \
    bf16x8 hf[4]; \
    _Pragma("unroll") for (int kc=0;kc<4;++kc) hf[kc] = *(const bf16x8*)&hbuf[RB][b4][kc*32 + lg*8]; \
    f32x4 acc[4]; \
    _Pragma("unroll") for (int q=0;q<4;++q) acc[q]=fz4(); \
    _Pragma("unroll") for (int kc=0;kc<4;++kc) \
      _Pragma("unroll") for (int q=0;q<4;++q) acc[q] = MFMA(wf[q][kc], hf[kc], acc[q]); \
    float gv[4]; \
    _Pragma("unroll") for (int q=0;q<4;++q){ \
      f32x4 v = acc[q]; \
      float x01 = (rsel&1) ? v[1] : v[0]; \
      float x23 = (rsel&1) ? v[3] : v[2]; \
      gv[q] = ((rsel&2) ? x23 : x01) + gq[q]; } \
    float ii=sigm(gv[0]), ff=sigm(gv[1]), gg=tanhx(gv[2]), oo=sigm(gv[3]); \
    cs = ff*cs + ii*gg; \
    float hv = oo*tanhx(cs); \
    hs += hv; \
    hbuf[WB][b4][j0] = (__bf16)hv; \
    __syncthreads(); }

  for (int it=0; it<512; ++it){
    LSTM_STEP(0, 1, gA)
    LSTM_STEP(1, 0, gB)
  }
#undef LSTM_STEP
  lc[(bg*4+b4)*256 + dir*128 + j0] = hs*(1.f/1024.f);
}

// ---------------- MHA: two-sweep softmax column weights ----------------
template<int MODE>
__global__ __launch_bounds__(256,1) void k_mha(const float* __restrict__ qkv, float* __restrict__ rowsum,
                                               float* __restrict__ colw){
  int rb = blockIdx.x, h2 = blockIdx.y, b = blockIdx.z;
  __shared__ __bf16 Qs[256][136];
  __shared__ __bf16 Ks[128][136];
  int tid=threadIdx.x, l=tid&63, w=tid>>6, lr=l&15, lg=l>>4;
  {
    const float qs = LOG2E / sqrtf(128.0f);
    int row = tid;
    const float* p = qkv + ((size_t)(b*1024 + rb*256 + row))*1536 + h2*128;
    #pragma unroll
    for (int cc=0; cc<128; cc+=8){
      f32x4 u0 = *(const f32x4*)(p+cc), u1 = *(const f32x4*)(p+cc+4);
      bf16x8 v;
      #pragma unroll
      for (int j=0;j<4;++j){ v[j]=(__bf16)(u0[j]*qs); v[j+4]=(__bf16)(u1[j]*qs); }
      *(bf16x8*)&Qs[row][cc] = v;
    }
  }
  float rs[4][4];
  if (MODE==1){
    #pragma unroll
    for (int mf=0;mf<4;++mf){ rs[mf][0]=0.f; rs[mf][1]=0.f; rs[mf][2]=0.f; rs[mf][3]=0.f; }
  } else {
    #pragma unroll
    for (int mf=0;mf<4;++mf)
      #pragma unroll
      for (int r=0;r<4;++r)
        rs[mf][r] = 1.0f / rowsum[((size_t)(b*4+h2))*1024 + rb*256 + w*64 + mf*16 + lg*4 + r];
  }
  for (int mc=0; mc<8; ++mc){
    __syncthreads();
    {
      int row = tid>>1, co = (tid&1)*64;
      const float* p = qkv + ((size_t)(b*1024 + mc*128 + row))*1536 + 512 + h2*128 + co;
      #pragma unroll
      for (int cc=0; cc<64; cc+=8){
        f32x4 u0 = *(const f32x4*)(p+cc), u1 = *(const f32x4*)(p+cc+4);
        bf16x8 v;
        #pragma unroll
        for (int j=0;j<4;++j){ v[j]=(__bf16)u0[j]; v[j+4]=(__bf16)u1[j]; }
        *(bf16x8*)&Ks[row][co+cc] = v;
      }
    }
    __syncthreads();
    f32x4 acc[4][8];
    #pragma unroll
    for (int mf=0;mf<4;++mf)
      #pragma unroll
      for (int nf=0;nf<8;++nf) acc[mf][nf]=fz4();
    #pragma unroll
    for (int ks=0;ks<4;++ks){
      bf16x8 aF[4], bFv[8];
      #pragma unroll
      for (int mf=0;mf<4;++mf) aF[mf] = *(const bf16x8*)&Qs[w*64+mf*16+lr][ks*32+lg*8];
      #pragma unroll
      for (int nf=0;nf<8;++nf) bFv[nf] = *(const bf16x8*)&Ks[nf*16+lr][ks*32+lg*8];
      #pragma unroll
      for (int mf=0;mf<4;++mf)
        #pragma unroll
        for (int nf=0;nf<8;++nf) acc[mf][nf] = MFMA(aF[mf], bFv[nf], acc[mf][nf]);
    }
    if (MODE==1){
      #pragma unroll
      for (int mf=0;mf<4;++mf)
        #pragma unroll
        for (int nf=0;nf<8;++nf)
          #pragma unroll
          for (int r=0;r<4;++r) rs[mf][r] += exp2f(acc[mf][nf][r]);
    } else {
      #pragma unroll
      for (int nf=0;nf<8;++nf){
        float cv = 0.f;
        #pragma unroll
        for (int mf=0;mf<4;++mf)
          #pragma unroll
          for (int r=0;r<4;++r) cv += exp2f(acc[mf][nf][r])*rs[mf][r];
        cv += __shfl_xor(cv,16);
        cv += __shfl_xor(cv,32);
        if (lg==0)
          colw[(((size_t)(rb*4+w)*8 + b)*4 + h2)*1024 + mc*128 + nf*16 + lr] = cv;
      }
    }
  }
  if (MODE==1){
    #pragma unroll
    for (int mf=0;mf<4;++mf)
      #pragma unroll
      for (int r=0;r<4;++r){
        float v = rs[mf][r];
        v += __shfl_xor(v,1); v += __shfl_xor(v,2); v += __shfl_xor(v,4); v += __shfl_xor(v,8);
        if (lr==0) rowsum[((size_t)(b*4+h2))*1024 + rb*256 + w*64 + mf*16 + lg*4 + r] = v;
      }
  }
}

__global__ void k_mha3(const float* __restrict__ qkv, const float* __restrict__ colw, float* __restrict__ acm){
  int h2 = blockIdx.x & 3, b = blockIdx.x >> 2;
  int tid = threadIdx.x;
  __shared__ float cwred[1024];
  for (int m=tid; m<1024; m+=256){
    float cw=0.f;
    #pragma unroll
    for (int t16=0;t16<16;++t16) cw += colw[(((size_t)t16*8 + b)*4 + h2)*1024 + m];
    cwred[m]=cw;
  }
  __syncthreads();
  int e = tid & 127, half = tid >> 7;
  float s = 0.f;
  for (int m = half*512; m < half*512+512; ++m)
    s += cwred[m] * qkv[((size_t)(b*1024+m))*1536 + 1024 + h2*128 + e];
  __shared__ float red[256];
  red[tid]=s; __syncthreads();
  if (tid<128) acm[((size_t)(b*4+h2))*128 + e] = (red[tid]+red[tid+128])*(1.f/1024.f);
}

__global__ void k_xmean(const float* __restrict__ x, float* __restrict__ xmean){
  int b = blockIdx.x, c = threadIdx.x; // 512
  float s=0.f;
  for (int n=0;n<1024;++n) s += x[((size_t)(b*1024+n))*512 + c];
  xmean[b*512+c] = s*(1.f/1024.f);
}

__global__ __launch_bounds__(256) void k_coeffs(float* __restrict__ ws,
                        const float* __restrict__ mow, const float* __restrict__ mob,
                        const float* __restrict__ ca_w1, const float* __restrict__ ca_b1,
                        const float* __restrict__ ca_w2, const float* __restrict__ ca_b2){
  int b = blockIdx.x, tid = threadIdx.x;
  __shared__ float av[512], comb[512], hid[256];
  for (int i=tid;i<512;i+=256) av[i] = ws[OFF_ACM + b*512 + i];
  __syncthreads();
  for (int c=tid;c<512;c+=256){
    float s = mob[c];
    for (int k=0;k<512;++k) s += mow[(size_t)c*512+k]*av[k];
    comb[c] = s + ws[OFF_XMEAN + b*512 + c] + ((c<256) ? ws[OFF_LC + b*256 + c] : 0.f);
  }
  __syncthreads();
  for (int j=tid;j<256;j+=256){
    float s = ca_b1[j];
    for (int k=0;k<512;++k) s += ca_w1[(size_t)j*512+k]*comb[k];
    hid[j] = fmaxf(s,0.f);
  }
  __syncthreads();
  if (tid<32){
    float s = ca_b2[tid];
    for (int k=0;k<256;++k) s += ca_w2[tid*256+k]*hid[k];
    ws[OFF_COEF + b*32 + tid] = 1.f/(1.f+expf(-s));
  }
}

// ---------------- spectral: forward DFT + filter -> Hb ----------------
__global__ __launch_bounds__(256,2) void k_spec1(const float* __restrict__ qkv, float* __restrict__ ws){
  int qk = blockIdx.x, h = blockIdx.y, b = blockIdx.z;
  int colbase = qk*512 + h*64;
  int tid=threadIdx.x, l=tid&63, w=tid>>6, lr=l&15, lg=l>>4;
  __shared__ __bf16 tT[64][520];
  __shared__ float M1[32][64];
  __shared__ float G2[256][2];
  const __bf16* w1cs = (const __bf16*)(ws + OFF_W1CS);
  f32x4 acc[2]; acc[0]=fz4(); acc[1]=fz4();
  for (int c0=0; c0<2; ++c0){
    __syncthreads();
    {
      int p = tid;
      int m0 = c0*512 + 2*p;
      const float* r0 = qkv + ((size_t)(b*1024 + m0))*1536 + colbase;
      const float* r1 = r0 + 1536;
      #pragma unroll
      for (int e=0;e<64;e+=4){
        f32x4 u0 = *(const f32x4*)(r0+e);
        f32x4 u1 = *(const f32x4*)(r1+e);
        #pragma unroll
        for (int j=0;j<4;++j) *(unsigned*)&tT[e+j][2*p] = pk2(u0[j], u1[j]);
      }
    }
    __syncthreads();
    for (int ks=0; ks<16; ++ks){
      bf16x8 bf = *(const bf16x8*)&tT[w*16+lr][ks*32+lg*8];
      #pragma unroll
      for (int mf=0;mf<2;++mf){
        bf16x8 af = *(const bf16x8*)(w1cs + (size_t)(mf*16+lr)*1024 + c0*512 + ks*32 + lg*8);
        acc[mf] = MFMA(af, bf, acc[mf]);
      }
    }
  }
  #pragma unroll
  for (int mf=0;mf<2;++mf)
    #pragma unroll
    for (int r=0;r<4;++r) M1[mf*16 + lg*4 + r][w*16 + lr] = acc[mf][r];
  __syncthreads();
  {
    int k1 = tid>>4, k2 = tid&15;
    float tfr=0.f, tfi=0.f;
    const float* w2 = ws + OFF_W2;
    for (int e=0;e<64;++e){
      float mr = M1[k1][e], mi = M1[16+k1][e];
      float cr = w2[(e*16+k2)*2], ci = w2[(e*16+k2)*2+1];
      tfr += mr*cr - mi*ci;
      tfi += mr*ci + mi*cr;
    }
    float wr = ws[OFF_WEFF + ((size_t)h*256 + k1*16 + k2)*2];
    float wi = ws[OFF_WEFF + ((size_t)h*256 + k1*16 + k2)*2 + 1];
    G2[tid][0] = tfr*wr - tfi*wi;
    G2[tid][1] = tfr*wi + tfi*wr;
  }
  __syncthreads();
  __bf16* hb = (__bf16*)(ws + OFF_HB) + ((size_t)((b*8+h)*2+qk))*2048;
  const float* w2 = ws + OFF_W2;
  for (int f=tid; f<1024; f+=256){
    int k1 = f>>6, d = f&63;
    float hr=0.f, hi=0.f;
    #pragma unroll
    for (int k2=0;k2<16;++k2){
      float gr=G2[k1*16+k2][0], gi=G2[k1*16+k2][1];
      float sc = k2 ? 2.f : 1.f;
      float cr = sc*w2[(d*16+k2)*2];
      float ci = -sc*w2[(d*16+k2)*2+1];
      hr += gr*cr - gi*ci;
      hi += gr*ci + gi*cr;
    }
    const float inv = 1.0f/65536.0f;
    hb[d*32 + k1]      = (__bf16)(hr*inv);
    hb[d*32 + 16 + k1] = (__bf16)(-hi*inv);
  }
}

// ---------------- spectral: inverse DFT apply (overwrite q/k) ----------------
__global__ __launch_bounds__(256,2) void k_spec2(float* __restrict__ qkv, const float* __restrict__ ws){
  int qk=blockIdx.x, h=blockIdx.y, b=blockIdx.z;
  int colbase = qk*512 + h*64;
  int tid=threadIdx.x, l=tid&63, w=tid>>6, lr=l&15, lg=l>>4;
  __shared__ __bf16 hbl[2048];
  const __bf16* hb = (const __bf16*)(ws + OFF_HB) + ((size_t)((b*8+h)*2+qk))*2048;
  *(bf16x8*)&hbl[tid*8] = *(const bf16x8*)&hb[tid*8];
  __syncthreads();
  const __bf16* w1t = (const __bf16*)(ws + OFF_W1T);
  bf16x8 bF[4];
  #pragma unroll
  for (int nf=0;nf<4;++nf) bF[nf] = *(const bf16x8*)&hbl[(nf*16+lr)*32 + lg*8];
  for (int pass=0; pass<4; ++pass){
    int rowbase = w*256 + pass*64;
    f32x4 acc[4][4];
    #pragma unroll
    for (int mf=0;mf<4;++mf){ acc[mf][0]=fz4(); acc[mf][1]=fz4(); acc[mf][2]=fz4(); acc[mf][3]=fz4(); }
    #pragma unroll
    for (int mf=0;mf<4;++mf){
      bf16x8 aF = *(const bf16x8*)(w1t + (size_t)(rowbase+mf*16+lr)*32 + lg*8);
      #pragma unroll
      for (int nf=0;nf<4;++nf) acc[mf][nf] = MFMA(aF, bF[nf], acc[mf][nf]);
    }
    #pragma unroll
    for (int mf=0;mf<4;++mf)
      #pragma unroll
      for (int nf=0;nf<4;++nf)
        #pragma unroll
        for (int r=0;r<4;++r){
          int n = rowbase + mf*16 + lg*4 + r;
          int d = nf*16 + lr;
          qkv[((size_t)(b*1024+n))*1536 + colbase + d] = acc[mf][nf][r];
        }
  }
}

// ---------------- polarity linear attention ----------------
__global__ __launch_bounds__(256,1) void k_polar(const float* __restrict__ qkv, const float* __restrict__ ws,
                                                 float* __restrict__ accum, int s){
  int h = blockIdx.x, b = blockIdx.y;
  int tid=threadIdx.x, l=tid&63, w=tid>>6, lr=l&15, lg=l>>4;
  __shared__ float plds[23200];
  __bf16* kpT = (__bf16*)plds;
  __bf16* knT = (__bf16*)((char*)plds + 17408);
  __bf16* vT  = (__bf16*)((char*)plds + 34816);
  float* scal = (float*)((char*)plds + 92416);
  float* pvs  = scal + 8;
  if (tid<4)  scal[tid] = ws[OFF_COEF + b*32 + h*4 + tid];
  if (tid==4) scal[4] = ws[OFF_GMIX + 2*h];
  if (tid==5) scal[5] = ws[OFF_GMIX + 2*h+1];
  if (tid<64) pvs[tid] = ws[OFF_PPOW + ((size_t)s*8+h)*64 + tid];
  for (int i=tid; i<16*136; i+=256) vT[64*136 + i] = (__bf16)((i<136)?1.0f:0.0f);
  f32x4 acc[4][5];
  #pragma unroll
  for (int mf=0;mf<4;++mf)
    #pragma unroll
    for (int nf=0;nf<5;++nf) acc[mf][nf]=fz4();
  for (int mc=0;mc<8;++mc){
    __syncthreads();
    #pragma unroll
    for (int it=0; it<16; ++it){
      int flat = tid + 256*it;
      int d = flat & 63, np = flat >> 6;
      int n = mc*128 + 2*np;
      const float* kr = qkv + ((size_t)(b*1024+n))*1536 + 512 + h*64 + d;
      const float* vr = qkv + ((size_t)(b*1024+n))*1536 + 1024 + h*64 + d;
      float p = pvs[d];
      float k0=kr[0], k1=kr[1536], v0=vr[0], v1=vr[1536];
      float kp0,kn0,kp1,kn1;
      powpair(k0,p,kp0,kn0); powpair(k1,p,kp1,kn1);
      *(unsigned*)&kpT[d*136 + 2*np] = pk2(kp0,kp1);
      *(unsigned*)&knT[d*136 + 2*np] = pk2(kn0,kn1);
      *(unsigned*)&vT [d*136 + 2*np] = pk2(v0,v1);
    }
    __syncthreads();
    const __bf16* A = (w&2)?knT:kpT;
    int kh = (w&1)*64;
    #pragma unroll
    for (int ks=0;ks<2;++ks){
      bf16x8 aF[4];
      #pragma unroll
      for (int mf=0;mf<4;++mf) aF[mf] = *(const bf16x8*)&A[(mf*16+lr)*136 + kh + ks*32 + lg*8];
      #pragma unroll
      for (int nf=0;nf<5;++nf){
        bf16x8 bFv = *(const bf16x8*)&vT[(nf*16+lr)*136 + kh + ks*32 + lg*8];
        #pragma unroll
        for (int mf=0;mf<4;++mf) acc[mf][nf] = MFMA(aF[mf], bFv, acc[mf][nf]);
      }
    }
  }
  __syncthreads();
  float* kvf = plds; // [2][64][80]
  if ((w&1)==0){
    int mat = w>>1;
    #pragma unroll
    for (int mf=0;mf<4;++mf)
      #pragma unroll
      for (int nf=0;nf<5;++nf)
        #pragma unroll
        for (int r=0;r<4;++r)
          kvf[((size_t)mat*64 + mf*16+lg*4+r)*80 + nf*16+lr] = acc[mf][nf][r];
  }
  __syncthreads();
  if (w&1){
    int mat = w>>1;
    #pragma unroll
    for (int mf=0;mf<4;++mf)
      #pragma unroll
      for (int nf=0;nf<5;++nf)
        #pragma unroll
        for (int r=0;r<4;++r)
          kvf[((size_t)mat*64 + mf*16+lg*4+r)*80 + nf*16+lr] += acc[mf][nf][r];
  }
  __syncthreads();
  __bf16* Bm = (__bf16*)((char*)plds + 69632);
  {
    float c0=scal[0], c1=scal[1], c2=scal[2], c3=scal[3], g0=scal[4], g1=scal[5];
    for (int f=tid; f<80*128; f+=256){
      int e=f>>7, kk=f&127;
      float v;
      if (e<64){
        if (kk<64) v = g0*c0*kvf[kk*80+e] + g1*c2*kvf[(64+kk)*80+e];
        else { int k2=kk-64; v = g0*c1*kvf[(64+k2)*80+e] + g1*c3*kvf[k2*80+e]; }
      } else if (e==64){
        v = (kk<64) ? kvf[kk*80+64] : kvf[(64+(kk-64))*80+64];
      } else v = 0.f;
      Bm[e*136+kk] = (__bf16)v;
    }
  }
  __syncthreads();
  bf16x8 bF2[5][4];
  #pragma unroll
  for (int nf=0;nf<5;++nf)
    #pragma unroll
    for (int ks=0;ks<4;++ks) bF2[nf][ks] = *(const bf16x8*)&Bm[(nf*16+lr)*136 + ks*32 + lg*8];
  __bf16* At = (__bf16*)plds;
  float* zb = (float*)((char*)plds + 91392);
  for (int pass=0; pass<4; ++pass){
    __syncthreads();
    #pragma unroll
    for (int it=0; it<16; ++it){
      int flat = tid + 256*it;
      int row = flat>>4, dg = flat&15;
      int n = pass*256 + row;
      const float* qr = qkv + ((size_t)(b*1024+n))*1536 + h*64 + dg*4;
      f32x4 u = *(const f32x4*)qr;
      float qp[4], qn[4];
      #pragma unroll
      for (int j=0;j<4;++j) powpair(u[j], pvs[dg*4+j], qp[j], qn[j]);
      *(unsigned*)&At[row*136 + dg*4]        = pk2(qp[0],qp[1]);
      *(unsigned*)&At[row*136 + dg*4+2]      = pk2(qp[2],qp[3]);
      *(unsigned*)&At[row*136 + 64 + dg*4]   = pk2(qn[0],qn[1]);
      *(unsigned*)&At[row*136 + 64 + dg*4+2] = pk2(qn[2],qn[3]);
    }
    __syncthreads();
    f32x4 a2[4][5];
    #pragma unroll
    for (int mf=0;mf<4;++mf)
      #pragma unroll
      for (int nf=0;nf<5;++nf) a2[mf][nf]=fz4();
    #pragma unroll
    for (int ks=0;ks<4;++ks){
      bf16x8 aF[4];
      #pragma unroll
      for (int mf=0;mf<4;++mf) aF[mf] = *(const bf16x8*)&At[(w*64+mf*16+lr)*136 + ks*32 + lg*8];
      #pragma unroll
      for (int nf=0;nf<5;++nf)
        #pragma unroll
        for (int mf=0;mf<4;++mf) a2[mf][nf] = MFMA(aF[mf], bF2[nf][ks], a2[mf][nf]);
    }
    if (lr==0){
      #pragma unroll
      for (int mf=0;mf<4;++mf)
        #pragma unroll
        for (int r=0;r<4;++r) zb[w*64 + mf*16 + lg*4 + r] = a2[mf][4][r] + 1e-6f;
    }
    __syncthreads();
    #pragma unroll
    for (int mf=0;mf<4;++mf){
      float rz[4];
      #pragma unroll
      for (int r=0;r<4;++r) rz[r] = 1.0f / zb[w*64 + mf*16 + lg*4 + r];
      #pragma unroll
      for (int nf=0;nf<4;++nf)
        #pragma unroll
        for (int r=0;r<4;++r){
          int n = pass*256 + w*64 + mf*16 + lg*4 + r;
          int e = nf*16 + lr;
          size_t oi = ((size_t)((b*8+h)*1024) + n)*64 + e;
          float v = a2[mf][nf][r]*rz[r];
          if (s==0) accum[oi] = v; else accum[oi] += v;
        }
    }
  }
}

// ---------------- combined 9x9 depthwise conv ----------------
__global__ __launch_bounds__(256,2) void k_conv(const float* __restrict__ qkv, const float* __restrict__ ws,
                                                float* __restrict__ accum){
  int bid = blockIdx.x;
  int sl = bid & 3, h = (bid>>2)&7, b = bid>>5;
  int tid = threadIdx.x;
  __shared__ float vs[1024][16];
  __shared__ float wc[16][81];
  __shared__ float cb[16];
  for (int it=0; it<64; ++it){
    int flat = tid + 256*it;
    int c = flat & 15, pix = flat>>4;
    vs[pix][c] = qkv[((size_t)(b*1024+pix))*1536 + 1024 + h*64 + sl*16 + c];
  }
  for (int f=tid; f<16*81; f+=256) wc[f/81][f%81] = ws[OFF_CONV9 + (size_t)(sl*16 + f/81)*81 + (f%81)];
  if (tid<16) cb[tid] = ws[OFF_CBIAS + sl*16 + tid];
  __syncthreads();
  #pragma unroll
  for (int cc=0; cc<2; ++cc){
    int col = tid + 256*cc;
    int c = col & 15, x = col >> 4;
    float a[32];
    #pragma unroll
    for (int y=0;y<32;++y) a[y]=0.f;
    #pragma unroll
    for (int dx=-4; dx<=4; ++dx){
      int xx = x+dx;
      bool xv = (xx>=0)&&(xx<32);
      float colv[40];
      #pragma unroll
      for (int i=0;i<40;++i){
        int yy = i-4;
        colv[i] = (xv && yy>=0 && yy<32) ? vs[yy*32+xx][c] : 0.f;
      }
      #pragma unroll
      for (int dy=0; dy<9; ++dy){
        float wv = wc[c][dy*9 + dx+4];
        #pragma unroll
        for (int y=0;y<32;++y) a[y] += wv*colv[y+dy];
      }
    }
    float bias = cb[c];
    #pragma unroll
    for (int y=0;y<32;++y){
      size_t oi = ((size_t)((b*8+h)*1024) + y*32 + x)*64 + sl*16 + c;
      accum[oi] += a[y] + bias;
    }
  }
}

__global__ void k_finalize(const float* __restrict__ accum, float* __restrict__ fin){
  int idx = blockIdx.x*256 + threadIdx.x;
  int c = idx & 511, n = (idx>>9)&1023, b = idx>>19;
  int h = c>>6, d = c&63;
  fin[idx] = accum[((size_t)((b*8+h)*1024)+n)*64 + d] * (1.0f/3.0f);
}

// ---------------- launch ----------------
extern "C" void kernel_launch(void* const* d_in, const int* in_sizes, int n_in,
                              void* d_out, int out_size, void* d_ws, size_t ws_size,
                              hipStream_t stream){
  const float* x        = (const float*)d_in[0];
  const float* qkv_w    = (const float*)d_in[3];
  const float* proj_w   = (const float*)d_in[4];
  const float* proj_b   = (const float*)d_in[5];
  const float* pos_sw   = (const float*)d_in[6];
  const float* neg_sw   = (const float*)d_in[7];
  const float* ca_w1    = (const float*)d_in[9];
  const float* ca_b1    = (const float*)d_in[10];
  const float* ca_w2    = (const float*)d_in[11];
  const float* ca_b2    = (const float*)d_in[12];
  const float* wih_f    = (const float*)d_in[13];
  const float* whh_f    = (const float*)d_in[14];
  const float* bih_f    = (const float*)d_in[15];
  const float* bhh_f    = (const float*)d_in[16];
  const float* wih_b    = (const float*)d_in[17];
  const float* whh_b    = (const float*)d_in[18];
  const float* bih_b    = (const float*)d_in[19];
  const float* bhh_b    = (const float*)d_in[20];
  const float* mha_in_w = (const float*)d_in[21];
  const float* mha_in_b = (const float*)d_in[22];
  const float* mha_out_w= (const float*)d_in[23];
  const float* mha_out_b= (const float*)d_in[24];
  const float* ge_b1    = (const float*)d_in[26];
  const float* ge_w2    = (const float*)d_in[27];
  const float* ge_b2    = (const float*)d_in[28];
  const float* spw      = (const float*)d_in[29];
  const float* w5 = (const float*)d_in[30]; const float* b5 = (const float*)d_in[31];
  const float* w7 = (const float*)d_in[32]; const float* b7 = (const float*)d_in[33];
  const float* w9 = (const float*)d_in[34]; const float* b9 = (const float*)d_in[35];
  const float* mode_w = (const float*)d_in[36];
  float* ws  = (float*)d_ws;
  float* out = (float*)d_out;

  k_const<<<1,256,0,stream>>>(ge_b1, ge_w2, ge_b2, mode_w, w5,b5,w7,b7,w9,b9,
                              pos_sw, neg_sw, spw, bih_f,bhh_f,bih_b,bhh_b, ws);
  // LSTM input gemms (gates in (b,t,512)) -> transpose -> scan
  k_gemm<<<dim3(4,64),256,0,stream>>>(x, wih_f, ws+OFF_LBIAS,     ws+OFF_R0,          8192,512,512);
  k_gemm<<<dim3(4,64),256,0,stream>>>(x, wih_b, ws+OFF_LBIAS+512, ws+OFF_R0+4194304,  8192,512,512);
  k_gxt<<<2048,256,0,stream>>>(ws+OFF_R0, ws+OFF_GXT);
  k_lstm_scan<<<4,512,0,stream>>>(whh_f, whh_b, ws+OFF_GXT, ws+OFF_LC);
  // MHA branch
  k_gemm<<<dim3(12,64),256,0,stream>>>(x, mha_in_w, mha_in_b, ws+OFF_R0, 8192,1536,512);
  k_mha<1><<<dim3(4,4,8),256,0,stream>>>(ws+OFF_R0, ws+OFF_ROWSUM, ws+OFF_COLW);
  k_mha<2><<<dim3(4,4,8),256,0,stream>>>(ws+OFF_R0, ws+OFF_ROWSUM, ws+OFF_COLW);
  k_mha3<<<32,256,0,stream>>>(ws+OFF_R0, ws+OFF_COLW, ws+OFF_ACM);
  k_xmean<<<8,512,0,stream>>>(x, ws+OFF_XMEAN);
  k_coeffs<<<8,256,0,stream>>>(ws, mha_out_w, mha_out_b, ca_w1, ca_b1, ca_w2, ca_b2);
  // scales
  for (int s=0; s<3; ++s){
    k_gemm<<<dim3(12,64),256,0,stream>>>(x, qkv_w + (size_t)s*1536*512, nullptr, ws+OFF_R0, 8192,1536,512);
    k_spec1<<<dim3(2,8,8),256,0,stream>>>(ws+OFF_R0, ws);
    k_spec2<<<dim3(2,8,8),256,0,stream>>>(ws+OFF_R0, ws);
    k_polar<<<dim3(8,8),256,0,stream>>>(ws+OFF_R0, ws, ws+OFF_ACCUM, s);
    k_conv<<<256,256,0,stream>>>(ws+OFF_R0, ws, ws+OFF_ACCUM);
  }
  k_finalize<<<16384,256,0,stream>>>(ws+OFF_ACCUM, ws+OFF_FINAL);
  k_gemm<<<dim3(4,64),256,0,stream>>>(ws+OFF_FINAL, proj_w, proj_b, out, 8192,512,512);
}

// Round 6
// 1918.390 us; speedup vs baseline: 1.8236x; 1.0330x over previous
//
#include <hip/hip_runtime.h>
#include <hip/hip_bf16.h>
#include <math.h>

typedef __bf16 bf16x8 __attribute__((ext_vector_type(8)));
typedef float  f32x4  __attribute__((ext_vector_type(4)));

#define MFMA(a,b,c) __builtin_amdgcn_mfma_f32_16x16x32_bf16(a, b, c, 0, 0, 0)
#define LOG2E 1.4426950408889634f

// ---------------- workspace float offsets ----------------
static constexpr size_t OFF_R0    = 0;                       // 12,582,912 : gates(f,b) then qkv buffer
static constexpr size_t OFF_GXT   = 12582912;                // 8,388,608 : gxt -> later accum+final
static constexpr size_t OFF_ACCUM = OFF_GXT;                 // 4,194,304
static constexpr size_t OFF_FINAL = OFF_GXT + 4194304;       // 4,194,304
static constexpr size_t SOFF      = OFF_GXT + 8388608;
static constexpr size_t OFF_ROWSUM= SOFF;                    // 32768
static constexpr size_t OFF_COLW  = OFF_ROWSUM + 32768;      // 524288 (16 deterministic partials)
static constexpr size_t OFF_ACM   = OFF_COLW + 524288;       // 4096
static constexpr size_t OFF_XMEAN = OFF_ACM + 4096;          // 4096
static constexpr size_t OFF_LC    = OFF_XMEAN + 4096;        // 2048
static constexpr size_t OFF_COEF  = OFF_LC + 2048;           // 256
static constexpr size_t OFF_GMIX  = OFF_COEF + 256;          // 16
static constexpr size_t OFF_MW    = OFF_GMIX + 16;           // 4
static constexpr size_t OFF_CONV9 = OFF_MW + 4;              // 5184
static constexpr size_t OFF_CBIAS = OFF_CONV9 + 5184;        // 64
static constexpr size_t OFF_WEFF  = OFF_CBIAS + 64;          // 4096 (8*16*16 complex)
static constexpr size_t OFF_PPOW  = OFF_WEFF + 4096;         // 1536
static constexpr size_t OFF_LBIAS = OFF_PPOW + 1536;         // 1024
static constexpr size_t OFF_W2    = OFF_LBIAS + 1024;        // 2048 (64*16 complex, e^{-i})
static constexpr size_t OFF_W1CS  = OFF_W2 + 2048;           // 16384 floats = bf16[32][1024]
static constexpr size_t OFF_W1T   = OFF_W1CS + 16384;        // 16384 floats = bf16[1024][32]
static constexpr size_t OFF_HB    = OFF_W1T + 16384;         // 131072 floats = bf16[128][2048]

__device__ __forceinline__ float sigm(float x){ return __builtin_amdgcn_rcpf(1.0f + exp2f(-LOG2E*x)); }
__device__ __forceinline__ float tanhx(float x){ return 2.0f*__builtin_amdgcn_rcpf(1.0f + exp2f(-2.0f*LOG2E*x)) - 1.0f; }
__device__ __forceinline__ unsigned pk2(float a, float b){
  union { __bf16 h[2]; unsigned u; } z; z.h[0]=(__bf16)a; z.h[1]=(__bf16)b; return z.u;
}
__device__ __forceinline__ void powpair(float t, float p, float& pos, float& neg){
  float a = fabsf(t);
  float v = (a > 0.f) ? exp2f(p * __log2f(a)) : 0.f;
  pos = (t > 0.f) ? v : 0.f;
  neg = (t < 0.f) ? v : 0.f;
}
__device__ __forceinline__ f32x4 fz4(){ return (f32x4){0.f,0.f,0.f,0.f}; }

// ---------------- constants / tables ----------------
__global__ void k_const(const float* __restrict__ ge_b1, const float* __restrict__ ge_w2,
                        const float* __restrict__ ge_b2, const float* __restrict__ mode_w,
                        const float* __restrict__ w5, const float* __restrict__ b5,
                        const float* __restrict__ w7, const float* __restrict__ b7,
                        const float* __restrict__ w9, const float* __restrict__ b9,
                        const float* __restrict__ pos_sw, const float* __restrict__ neg_sw,
                        const float* __restrict__ spw,
                        const float* __restrict__ bih_f, const float* __restrict__ bhh_f,
                        const float* __restrict__ bih_b, const float* __restrict__ bhh_b,
                        float* __restrict__ ws){
  int tid = threadIdx.x; // 256
  __shared__ float mw[3];
  __shared__ float tgh[256];
  __shared__ float sbuf[16];
  tgh[tid] = tanhf(ge_b1[tid]);
  if (tid == 0){
    float m0=mode_w[0], m1=mode_w[1], m2=mode_w[2];
    float mx = fmaxf(m0, fmaxf(m1,m2));
    float e0=expf(m0-mx), e1=expf(m1-mx), e2=expf(m2-mx);
    float s = e0+e1+e2;
    mw[0]=e0/s; mw[1]=e1/s; mw[2]=e2/s;
    ws[OFF_MW+0]=mw[0]; ws[OFF_MW+1]=mw[1]; ws[OFF_MW+2]=mw[2];
  }
  __syncthreads();
  if (tid < 16){
    float s = ge_b2[tid];
    for (int i=0;i<256;++i) s += ge_w2[tid*256+i]*tgh[i];
    sbuf[tid] = s;
  }
  __syncthreads();
  if (tid < 8){
    float a = sbuf[2*tid], b = sbuf[2*tid+1];
    float m = fmaxf(a,b);
    float ea = expf(a-m), eb = expf(b-m);
    ws[OFF_GMIX+2*tid]   = ea/(ea+eb);
    ws[OFF_GMIX+2*tid+1] = eb/(ea+eb);
  }
  for (int j=tid;j<512;j+=256){
    ws[OFF_LBIAS+j]     = bih_f[j]+bhh_f[j];
    ws[OFF_LBIAS+512+j] = bih_b[j]+bhh_b[j];
  }
  for (int f=tid; f<5184; f+=256){
    int d=f/81, t=f%81, ky=t/9, kx=t%9, dy=ky-4, dx=kx-4;
    float v = mw[2]*w9[d*81+t];
    if (dy>=-3 && dy<=3 && dx>=-3 && dx<=3) v += mw[1]*w7[d*49 + (dy+3)*7 + (dx+3)];
    if (dy>=-2 && dy<=2 && dx>=-2 && dx<=2) v += mw[0]*w5[d*25 + (dy+2)*5 + (dx+2)];
    ws[OFF_CONV9+f] = v;
  }
  if (tid<64) ws[OFF_CBIAS+tid] = mw[0]*b5[tid]+mw[1]*b7[tid]+mw[2]*b9[tid];
  // w_eff = wp + (1/16) wn   (softmax(spec_mix).mean(-1) == 1/16 exactly)
  for (int f=tid; f<2048; f+=256){
    int h=f>>8, k1=(f>>4)&15, k2=f&15;
    int src = ((h*16+k1)*64 + k2)*2;
    ws[OFF_WEFF+2*f]   = pos_sw[src]   + 0.0625f*neg_sw[src];
    ws[OFF_WEFF+2*f+1] = pos_sw[src+1] + 0.0625f*neg_sw[src+1];
  }
  for (int f=tid; f<1536; f+=256) ws[OFF_PPOW+f] = 1.0f + fabsf(spw[f]);
  // W2 (64x16 complex e^{-i 2pi e k2/64})
  for (int f=tid; f<1024; f+=256){
    int e=f>>4, k2=f&15; int ph=(e*k2)&63;
    float th = (float)ph * (6.283185307179586f/64.0f);
    ws[OFF_W2+2*f]   = cosf(th);
    ws[OFF_W2+2*f+1] = -sinf(th);
  }
  // W1CS bf16 [32][1024]: rows 0..15 cos, rows 16..31 -sin  (forward DFT)
  __bf16* w1cs = (__bf16*)(ws + OFF_W1CS);
  for (int f=tid; f<32768; f+=256){
    int r=f>>10, m=f&1023; int k1=r&15; int ph=(k1*m)&1023;
    float th = (float)ph * (6.283185307179586f/1024.0f);
    w1cs[f] = (__bf16)((r<16)?cosf(th):-sinf(th));
  }
  // W1T bf16 [1024][32]: cols 0..15 cos, cols 16..31 +sin (inverse DFT)
  __bf16* w1t = (__bf16*)(ws + OFF_W1T);
  for (int f=tid; f<32768; f+=256){
    int n=f>>5, r=f&31; int k1=r&15; int ph=(k1*n)&1023;
    float th = (float)ph * (6.283185307179586f/1024.0f);
    w1t[f] = (__bf16)((r<16)?cosf(th):sinf(th));
  }
}

// ---------------- generic GEMM: C[M,N] = A[M,K] @ W[N,K]^T (+bias), fp32 io, bf16 mfma ----------------
__global__ __launch_bounds__(256,2) void k_gemm(const float* __restrict__ A, const float* __restrict__ W,
                                                const float* __restrict__ bias, float* __restrict__ C,
                                                int M, int N, int K){
  __shared__ __bf16 As[128][40];
  __shared__ __bf16 Ws[128][40];
  int tid = threadIdx.x;
  int n0 = blockIdx.x * 128, m0 = blockIdx.y * 128;
  int l = tid & 63, wid = tid >> 6, lr = l & 15, lg = l >> 4;
  int wr = wid >> 1, wc = wid & 1;
  f32x4 acc[4][4];
  #pragma unroll
  for (int i=0;i<4;++i){ acc[i][0]=fz4(); acc[i][1]=fz4(); acc[i][2]=fz4(); acc[i][3]=fz4(); }
  int srow = tid >> 1, sk = (tid & 1) * 16;
  const float* Ap = A + (size_t)(m0 + srow) * K + sk;
  const float* Wp = W + (size_t)(n0 + srow) * K + sk;
  for (int k0 = 0; k0 < K; k0 += 32){
    f32x4 a0=*(const f32x4*)(Ap), a1=*(const f32x4*)(Ap+4), a2=*(const f32x4*)(Ap+8), a3=*(const f32x4*)(Ap+12);
    f32x4 w0=*(const f32x4*)(Wp), w1=*(const f32x4*)(Wp+4), w2=*(const f32x4*)(Wp+8), w3=*(const f32x4*)(Wp+12);
    Ap += 32; Wp += 32;
    __syncthreads();
    bf16x8 va, vb, wa, wb;
    #pragma unroll
    for (int j=0;j<4;++j){ va[j]=(__bf16)a0[j]; va[j+4]=(__bf16)a1[j]; vb[j]=(__bf16)a2[j]; vb[j+4]=(__bf16)a3[j];
                           wa[j]=(__bf16)w0[j]; wa[j+4]=(__bf16)w1[j]; wb[j]=(__bf16)w2[j]; wb[j+4]=(__bf16)w3[j]; }
    *(bf16x8*)&As[srow][sk]   = va;  *(bf16x8*)&As[srow][sk+8] = vb;
    *(bf16x8*)&Ws[srow][sk]   = wa;  *(bf16x8*)&Ws[srow][sk+8] = wb;
    __syncthreads();
    bf16x8 aF[4], bF[4];
    #pragma unroll
    for (int mf=0;mf<4;++mf) aF[mf] = *(const bf16x8*)&As[wr*64+mf*16+lr][lg*8];
    #pragma unroll
    for (int nf=0;nf<4;++nf) bF[nf] = *(const bf16x8*)&Ws[wc*64+nf*16+lr][lg*8];
    #pragma unroll
    for (int mf=0;mf<4;++mf)
      #pragma unroll
      for (int nf=0;nf<4;++nf) acc[mf][nf] = MFMA(aF[mf], bF[nf], acc[mf][nf]);
  }
  #pragma unroll
  for (int mf=0;mf<4;++mf)
    #pragma unroll
    for (int nf=0;nf<4;++nf){
      int row = m0 + wr*64 + mf*16 + lg*4;
      int col = n0 + wc*64 + nf*16 + lr;
      float bv = bias ? bias[col] : 0.f;
      #pragma unroll
      for (int r=0;r<4;++r) C[(size_t)(row+r)*N + col] = acc[mf][nf][r] + bv;
    }
}

// ---------------- transpose gates (b,t,j) -> (t,j,b) ----------------
__global__ void k_gxt(const float* __restrict__ gates, float* __restrict__ gxt){
  int t = blockIdx.x & 1023, dir = blockIdx.x >> 10;
  int tid = threadIdx.x;
  const float* g = gates + (size_t)dir*4194304;
  float* o = gxt + (size_t)dir*4194304 + (size_t)t*4096;
  for (int j=tid; j<512; j+=256){
    float vv[8];
    #pragma unroll
    for (int b=0;b<8;++b) vv[b] = g[((size_t)b*1024 + t)*512 + j];
    f32x4 u0 = {vv[0],vv[1],vv[2],vv[3]}, u1 = {vv[4],vv[5],vv[6],vv[7]};
    *(f32x4*)(o + (size_t)j*8)     = u0;
    *(f32x4*)(o + (size_t)j*8 + 4) = u1;
  }
}

// ---------------- LSTM scan v5: 4 blocks = 2 dir x 2 batch-groups, raw lgkm-only barrier, 4-deep prefetch ----------------
// gxt layout: (dir, t, j(512), b(8)) f32.  h in LDS [2][4][132] bf16 (double-buffered).
__global__ __launch_bounds__(512,1) void k_lstm_scan(const float* __restrict__ whh_f,
                                                     const float* __restrict__ whh_b,
                                                     const float* __restrict__ gxt,
                                                     float* __restrict__ lc){
  int dir = blockIdx.x >> 1, bg = blockIdx.x & 1;
  const float* __restrict__ whh = dir ? whh_b : whh_f;
  const float* gx0 = gxt + (size_t)dir*4194304;
  int tid=threadIdx.x, w=tid>>6, l=tid&63;
  int lr=l&15, lg=l>>4;          // MFMA row-within-tile and k-group
  int b4 = l&3, rsel = (l>>2)&3; // batch column (duplicated over bits 2-3 of col), row select
  // Weight fragments: A[row = q*128 + w*16 + lr][k = kc*32 + lg*8 + e]
  bf16x8 wf[4][4];
  #pragma unroll
  for (int q=0;q<4;++q)
    #pragma unroll
    for (int kc=0;kc<4;++kc){
      const float* p = whh + (size_t)(q*128 + w*16 + lr)*128 + kc*32 + lg*8;
      bf16x8 v;
      #pragma unroll
      for (int j=0;j<8;++j) v[j]=(__bf16)p[j];
      wf[q][kc]=v;
    }
  __shared__ __bf16 hbuf[2][4][132];
  for (int i=tid; i<2*4*132; i+=512) ((__bf16*)hbuf)[i] = (__bf16)0.0f;
  int j0 = w*16 + lg*4 + rsel;          // this lane's h row (0..127)
  int joff = j0*8 + bg*4 + b4;          // gxt per-t offset
  const float* ptr = gx0 + (dir ? (size_t)1023*4096 : 0);
  long tstride = dir ? -4096 : 4096;
  float cs=0.f, hs=0.f;
  // 4-deep rotating register prefetch: loads stay in flight across raw barriers
  float g0[4], g1[4], g2[4], g3[4];
  #pragma unroll
  for (int q=0;q<4;++q) g0[q] = ptr[q*1024+joff];
  ptr += tstride;
  #pragma unroll
  for (int q=0;q<4;++q) g1[q] = ptr[q*1024+joff];
  ptr += tstride;
  #pragma unroll
  for (int q=0;q<4;++q) g2[q] = ptr[q*1024+joff];
  ptr += tstride;
  #pragma unroll
  for (int q=0;q<4;++q) g3[q] = ptr[q*1024+joff];
  ptr += tstride;
  __syncthreads();

#define LSTM_STEP(RB, WB, G) { \
    float gq[4]; \
    _Pragma("unroll") for (int q=0;q<4;++q) gq[q]=G[q]; \
    _Pragma("unroll") for (int q=0;q<4;++q) G[q]=ptr[q*1024+joff]; \
    ptr += tstride; \
    bf16x8 hf[4]; \
    _Pragma("unroll") for (int kc=0;kc<4;++kc) hf[kc] = *(const bf16x8*)&hbuf[RB][b4][kc*32 + lg*8]; \
    f32x4 acc[4]; \
    _Pragma("unroll") for (int q=0;q<4;++q) acc[q]=fz4(); \
    _Pragma("unroll") for (int kc=0;kc<4;++kc) \
      _Pragma("unroll") for (int q=0;q<4;++q) acc[q] = MFMA(wf[q][kc], hf[kc], acc[q]); \
    float gv[4]; \
    _Pragma("unroll") for (int q=0;q<4;++q){ \
      f32x4 v = acc[q]; \
      float x01 = (rsel&1) ? v[1] : v[0]; \
      float x23 = (rsel&1) ? v[3] : v[2]; \
      gv[q] = ((rsel&2) ? x23 : x01) + gq[q]; } \
    float ii=sigm(gv[0]), ff=sigm(gv[1]), gg=tanhx(gv[2]), oo=sigm(gv[3]); \
    cs = ff*cs + ii*gg; \
    float hv = oo*tanhx(cs); \
    hs += hv; \
    hbuf[WB][b4][j0] = (__bf16)hv; \
    asm volatile("s_waitcnt lgkmcnt(0)" ::: "memory"); \
    __builtin_amdgcn_sched_barrier(0); \
    __builtin_amdgcn_s_barrier(); \
    __builtin_amdgcn_sched_barrier(0); }

  for (int it=0; it<256; ++it){
    LSTM_STEP(0, 1, g0)
    LSTM_STEP(1, 0, g1)
    LSTM_STEP(0, 1, g2)
    LSTM_STEP(1, 0, g3)
  }
#undef LSTM_STEP
  lc[(bg*4+b4)*256 + dir*128 + j0] = hs*(1.f/1024.f);
}

// ---------------- MHA: two-sweep softmax column weights ----------------
template<int MODE>
__global__ __launch_bounds__(256,1) void k_mha(const float* __restrict__ qkv, float* __restrict__ rowsum,
                                               float* __restrict__ colw){
  int rb = blockIdx.x, h2 = blockIdx.y, b = blockIdx.z;
  __shared__ __bf16 Qs[256][136];
  __shared__ __bf16 Ks[128][136];
  int tid=threadIdx.x, l=tid&63, w=tid>>6, lr=l&15, lg=l>>4;
  {
    const float qs = LOG2E / sqrtf(128.0f);
    int row = tid;
    const float* p = qkv + ((size_t)(b*1024 + rb*256 + row))*1536 + h2*128;
    #pragma unroll
    for (int cc=0; cc<128; cc+=8){
      f32x4 u0 = *(const f32x4*)(p+cc), u1 = *(const f32x4*)(p+cc+4);
      bf16x8 v;
      #pragma unroll
      for (int j=0;j<4;++j){ v[j]=(__bf16)(u0[j]*qs); v[j+4]=(__bf16)(u1[j]*qs); }
      *(bf16x8*)&Qs[row][cc] = v;
    }
  }
  float rs[4][4];
  if (MODE==1){
    #pragma unroll
    for (int mf=0;mf<4;++mf){ rs[mf][0]=0.f; rs[mf][1]=0.f; rs[mf][2]=0.f; rs[mf][3]=0.f; }
  } else {
    #pragma unroll
    for (int mf=0;mf<4;++mf)
      #pragma unroll
      for (int r=0;r<4;++r)
        rs[mf][r] = 1.0f / rowsum[((size_t)(b*4+h2))*1024 + rb*256 + w*64 + mf*16 + lg*4 + r];
  }
  for (int mc=0; mc<8; ++mc){
    __syncthreads();
    {
      int row = tid>>1, co = (tid&1)*64;
      const float* p = qkv + ((size_t)(b*1024 + mc*128 + row))*1536 + 512 + h2*128 + co;
      #pragma unroll
      for (int cc=0; cc<64; cc+=8){
        f32x4 u0 = *(const f32x4*)(p+cc), u1 = *(const f32x4*)(p+cc+4);
        bf16x8 v;
        #pragma unroll
        for (int j=0;j<4;++j){ v[j]=(__bf16)u0[j]; v[j+4]=(__bf16)u1[j]; }
        *(bf16x8*)&Ks[row][co+cc] = v;
      }
    }
    __syncthreads();
    f32x4 acc[4][8];
    #pragma unroll
    for (int mf=0;mf<4;++mf)
      #pragma unroll
      for (int nf=0;nf<8;++nf) acc[mf][nf]=fz4();
    #pragma unroll
    for (int ks=0;ks<4;++ks){
      bf16x8 aF[4], bFv[8];
      #pragma unroll
      for (int mf=0;mf<4;++mf) aF[mf] = *(const bf16x8*)&Qs[w*64+mf*16+lr][ks*32+lg*8];
      #pragma unroll
      for (int nf=0;nf<8;++nf) bFv[nf] = *(const bf16x8*)&Ks[nf*16+lr][ks*32+lg*8];
      #pragma unroll
      for (int mf=0;mf<4;++mf)
        #pragma unroll
        for (int nf=0;nf<8;++nf) acc[mf][nf] = MFMA(aF[mf], bFv[nf], acc[mf][nf]);
    }
    if (MODE==1){
      #pragma unroll
      for (int mf=0;mf<4;++mf)
        #pragma unroll
        for (int nf=0;nf<8;++nf)
          #pragma unroll
          for (int r=0;r<4;++r) rs[mf][r] += exp2f(acc[mf][nf][r]);
    } else {
      #pragma unroll
      for (int nf=0;nf<8;++nf){
        float cv = 0.f;
        #pragma unroll
        for (int mf=0;mf<4;++mf)
          #pragma unroll
          for (int r=0;r<4;++r) cv += exp2f(acc[mf][nf][r])*rs[mf][r];
        cv += __shfl_xor(cv,16);
        cv += __shfl_xor(cv,32);
        if (lg==0)
          colw[(((size_t)(rb*4+w)*8 + b)*4 + h2)*1024 + mc*128 + nf*16 + lr] = cv;
      }
    }
  }
  if (MODE==1){
    #pragma unroll
    for (int mf=0;mf<4;++mf)
      #pragma unroll
      for (int r=0;r<4;++r){
        float v = rs[mf][r];
        v += __shfl_xor(v,1); v += __shfl_xor(v,2); v += __shfl_xor(v,4); v += __shfl_xor(v,8);
        if (lr==0) rowsum[((size_t)(b*4+h2))*1024 + rb*256 + w*64 + mf*16 + lg*4 + r] = v;
      }
  }
}

__global__ void k_mha3(const float* __restrict__ qkv, const float* __restrict__ colw, float* __restrict__ acm){
  int h2 = blockIdx.x & 3, b = blockIdx.x >> 2;
  int tid = threadIdx.x;
  __shared__ float cwred[1024];
  for (int m=tid; m<1024; m+=256){
    float cw=0.f;
    #pragma unroll
    for (int t16=0;t16<16;++t16) cw += colw[(((size_t)t16*8 + b)*4 + h2)*1024 + m];
    cwred[m]=cw;
  }
  __syncthreads();
  int e = tid & 127, half = tid >> 7;
  float s = 0.f;
  for (int m = half*512; m < half*512+512; ++m)
    s += cwred[m] * qkv[((size_t)(b*1024+m))*1536 + 1024 + h2*128 + e];
  __shared__ float red[256];
  red[tid]=s; __syncthreads();
  if (tid<128) acm[((size_t)(b*4+h2))*128 + e] = (red[tid]+red[tid+128])*(1.f/1024.f);
}

__global__ void k_xmean(const float* __restrict__ x, float* __restrict__ xmean){
  int b = blockIdx.x, c = threadIdx.x; // 512
  float s=0.f;
  for (int n=0;n<1024;++n) s += x[((size_t)(b*1024+n))*512 + c];
  xmean[b*512+c] = s*(1.f/1024.f);
}

__global__ __launch_bounds__(256) void k_coeffs(float* __restrict__ ws,
                        const float* __restrict__ mow, const float* __restrict__ mob,
                        const float* __restrict__ ca_w1, const float* __restrict__ ca_b1,
                        const float* __restrict__ ca_w2, const float* __restrict__ ca_b2){
  int b = blockIdx.x, tid = threadIdx.x;
  __shared__ float av[512], comb[512], hid[256];
  for (int i=tid;i<512;i+=256) av[i] = ws[OFF_ACM + b*512 + i];
  __syncthreads();
  for (int c=tid;c<512;c+=256){
    float s = mob[c];
    for (int k=0;k<512;++k) s += mow[(size_t)c*512+k]*av[k];
    comb[c] = s + ws[OFF_XMEAN + b*512 + c] + ((c<256) ? ws[OFF_LC + b*256 + c] : 0.f);
  }
  __syncthreads();
  for (int j=tid;j<256;j+=256){
    float s = ca_b1[j];
    for (int k=0;k<512;++k) s += ca_w1[(size_t)j*512+k]*comb[k];
    hid[j] = fmaxf(s,0.f);
  }
  __syncthreads();
  if (tid<32){
    float s = ca_b2[tid];
    for (int k=0;k<256;++k) s += ca_w2[tid*256+k]*hid[k];
    ws[OFF_COEF + b*32 + tid] = 1.f/(1.f+expf(-s));
  }
}

// ---------------- spectral: forward DFT + filter -> Hb ----------------
__global__ __launch_bounds__(256,2) void k_spec1(const float* __restrict__ qkv, float* __restrict__ ws){
  int qk = blockIdx.x, h = blockIdx.y, b = blockIdx.z;
  int colbase = qk*512 + h*64;
  int tid=threadIdx.x, l=tid&63, w=tid>>6, lr=l&15, lg=l>>4;
  __shared__ __bf16 tT[64][520];
  __shared__ float M1[32][64];
  __shared__ float G2[256][2];
  const __bf16* w1cs = (const __bf16*)(ws + OFF_W1CS);
  f32x4 acc[2]; acc[0]=fz4(); acc[1]=fz4();
  for (int c0=0; c0<2; ++c0){
    __syncthreads();
    {
      int p = tid;
      int m0 = c0*512 + 2*p;
      const float* r0 = qkv + ((size_t)(b*1024 + m0))*1536 + colbase;
      const float* r1 = r0 + 1536;
      #pragma unroll
      for (int e=0;e<64;e+=4){
        f32x4 u0 = *(const f32x4*)(r0+e);
        f32x4 u1 = *(const f32x4*)(r1+e);
        #pragma unroll
        for (int j=0;j<4;++j) *(unsigned*)&tT[e+j][2*p] = pk2(u0[j], u1[j]);
      }
    }
    __syncthreads();
    for (int ks=0; ks<16; ++ks){
      bf16x8 bf = *(const bf16x8*)&tT[w*16+lr][ks*32+lg*8];
      #pragma unroll
      for (int mf=0;mf<2;++mf){
        bf16x8 af = *(const bf16x8*)(w1cs + (size_t)(mf*16+lr)*1024 + c0*512 + ks*32 + lg*8);
        acc[mf] = MFMA(af, bf, acc[mf]);
      }
    }
  }
  #pragma unroll
  for (int mf=0;mf<2;++mf)
    #pragma unroll
    for (int r=0;r<4;++r) M1[mf*16 + lg*4 + r][w*16 + lr] = acc[mf][r];
  __syncthreads();
  {
    int k1 = tid>>4, k2 = tid&15;
    float tfr=0.f, tfi=0.f;
    const float* w2 = ws + OFF_W2;
    for (int e=0;e<64;++e){
      float mr = M1[k1][e], mi = M1[16+k1][e];
      float cr = w2[(e*16+k2)*2], ci = w2[(e*16+k2)*2+1];
      tfr += mr*cr - mi*ci;
      tfi += mr*ci + mi*cr;
    }
    float wr = ws[OFF_WEFF + ((size_t)h*256 + k1*16 + k2)*2];
    float wi = ws[OFF_WEFF + ((size_t)h*256 + k1*16 + k2)*2 + 1];
    G2[tid][0] = tfr*wr - tfi*wi;
    G2[tid][1] = tfr*wi + tfi*wr;
  }
  __syncthreads();
  __bf16* hb = (__bf16*)(ws + OFF_HB) + ((size_t)((b*8+h)*2+qk))*2048;
  const float* w2 = ws + OFF_W2;
  for (int f=tid; f<1024; f+=256){
    int k1 = f>>6, d = f&63;
    float hr=0.f, hi=0.f;
    #pragma unroll
    for (int k2=0;k2<16;++k2){
      float gr=G2[k1*16+k2][0], gi=G2[k1*16+k2][1];
      float sc = k2 ? 2.f : 1.f;
      float cr = sc*w2[(d*16+k2)*2];
      float ci = -sc*w2[(d*16+k2)*2+1];
      hr += gr*cr - gi*ci;
      hi += gr*ci + gi*cr;
    }
    const float inv = 1.0f/65536.0f;
    hb[d*32 + k1]      = (__bf16)(hr*inv);
    hb[d*32 + 16 + k1] = (__bf16)(-hi*inv);
  }
}

// ---------------- spectral: inverse DFT apply (overwrite q/k) ----------------
__global__ __launch_bounds__(256,2) void k_spec2(float* __restrict__ qkv, const float* __restrict__ ws){
  int qk=blockIdx.x, h=blockIdx.y, b=blockIdx.z;
  int colbase = qk*512 + h*64;
  int tid=threadIdx.x, l=tid&63, w=tid>>6, lr=l&15, lg=l>>4;
  __shared__ __bf16 hbl[2048];
  const __bf16* hb = (const __bf16*)(ws + OFF_HB) + ((size_t)((b*8+h)*2+qk))*2048;
  *(bf16x8*)&hbl[tid*8] = *(const bf16x8*)&hb[tid*8];
  __syncthreads();
  const __bf16* w1t = (const __bf16*)(ws + OFF_W1T);
  bf16x8 bF[4];
  #pragma unroll
  for (int nf=0;nf<4;++nf) bF[nf] = *(const bf16x8*)&hbl[(nf*16+lr)*32 + lg*8];
  for (int pass=0; pass<4; ++pass){
    int rowbase = w*256 + pass*64;
    f32x4 acc[4][4];
    #pragma unroll
    for (int mf=0;mf<4;++mf){ acc[mf][0]=fz4(); acc[mf][1]=fz4(); acc[mf][2]=fz4(); acc[mf][3]=fz4(); }
    #pragma unroll
    for (int mf=0;mf<4;++mf){
      bf16x8 aF = *(const bf16x8*)(w1t + (size_t)(rowbase+mf*16+lr)*32 + lg*8);
      #pragma unroll
      for (int nf=0;nf<4;++nf) acc[mf][nf] = MFMA(aF, bF[nf], acc[mf][nf]);
    }
    #pragma unroll
    for (int mf=0;mf<4;++mf)
      #pragma unroll
      for (int nf=0;nf<4;++nf)
        #pragma unroll
        for (int r=0;r<4;++r){
          int n = rowbase + mf*16 + lg*4 + r;
          int d = nf*16 + lr;
          qkv[((size_t)(b*1024+n))*1536 + colbase + d] = acc[mf][nf][r];
        }
  }
}

// ---------------- polarity linear attention ----------------
__global__ __launch_bounds__(256,1) void k_polar(const float* __restrict__ qkv, const float* __restrict__ ws,
                                                 float* __restrict__ accum, int s){
  int h = blockIdx.x, b = blockIdx.y;
  int tid=threadIdx.x, l=tid&63, w=tid>>6, lr=l&15, lg=l>>4;
  __shared__ float plds[23200];
  __bf16* kpT = (__bf16*)plds;
  __bf16* knT = (__bf16*)((char*)plds + 17408);
  __bf16* vT  = (__bf16*)((char*)plds + 34816);
  float* scal = (float*)((char*)plds + 92416);
  float* pvs  = scal + 8;
  if (tid<4)  scal[tid] = ws[OFF_COEF + b*32 + h*4 + tid];
  if (tid==4) scal[4] = ws[OFF_GMIX + 2*h];
  if (tid==5) scal[5] = ws[OFF_GMIX + 2*h+1];
  if (tid<64) pvs[tid] = ws[OFF_PPOW + ((size_t)s*8+h)*64 + tid];
  for (int i=tid; i<16*136; i+=256) vT[64*136 + i] = (__bf16)((i<136)?1.0f:0.0f);
  f32x4 acc[4][5];
  #pragma unroll
  for (int mf=0;mf<4;++mf)
    #pragma unroll
    for (int nf=0;nf<5;++nf) acc[mf][nf]=fz4();
  for (int mc=0;mc<8;++mc){
    __syncthreads();
    #pragma unroll
    for (int it=0; it<16; ++it){
      int flat = tid + 256*it;
      int d = flat & 63, np = flat >> 6;
      int n = mc*128 + 2*np;
      const float* kr = qkv + ((size_t)(b*1024+n))*1536 + 512 + h*64 + d;
      const float* vr = qkv + ((size_t)(b*1024+n))*1536 + 1024 + h*64 + d;
      float p = pvs[d];
      float k0=kr[0], k1=kr[1536], v0=vr[0], v1=vr[1536];
      float kp0,kn0,kp1,kn1;
      powpair(k0,p,kp0,kn0); powpair(k1,p,kp1,kn1);
      *(unsigned*)&kpT[d*136 + 2*np] = pk2(kp0,kp1);
      *(unsigned*)&knT[d*136 + 2*np] = pk2(kn0,kn1);
      *(unsigned*)&vT [d*136 + 2*np] = pk2(v0,v1);
    }
    __syncthreads();
    const __bf16* A = (w&2)?knT:kpT;
    int kh = (w&1)*64;
    #pragma unroll
    for (int ks=0;ks<2;++ks){
      bf16x8 aF[4];
      #pragma unroll
      for (int mf=0;mf<4;++mf) aF[mf] = *(const bf16x8*)&A[(mf*16+lr)*136 + kh + ks*32 + lg*8];
      #pragma unroll
      for (int nf=0;nf<5;++nf){
        bf16x8 bFv = *(const bf16x8*)&vT[(nf*16+lr)*136 + kh + ks*32 + lg*8];
        #pragma unroll
        for (int mf=0;mf<4;++mf) acc[mf][nf] = MFMA(aF[mf], bFv, acc[mf][nf]);
      }
    }
  }
  __syncthreads();
  float* kvf = plds; // [2][64][80]
  if ((w&1)==0){
    int mat = w>>1;
    #pragma unroll
    for (int mf=0;mf<4;++mf)
      #pragma unroll
      for (int nf=0;nf<5;++nf)
        #pragma unroll
        for (int r=0;r<4;++r)
          kvf[((size_t)mat*64 + mf*16+lg*4+r)*80 + nf*16+lr] = acc[mf][nf][r];
  }
  __syncthreads();
  if (w&1){
    int mat = w>>1;
    #pragma unroll
    for (int mf=0;mf<4;++mf)
      #pragma unroll
      for (int nf=0;nf<5;++nf)
        #pragma unroll
        for (int r=0;r<4;++r)
          kvf[((size_t)mat*64 + mf*16+lg*4+r)*80 + nf*16+lr] += acc[mf][nf][r];
  }
  __syncthreads();
  __bf16* Bm = (__bf16*)((char*)plds + 69632);
  {
    float c0=scal[0], c1=scal[1], c2=scal[2], c3=scal[3], g0=scal[4], g1=scal[5];
    for (int f=tid; f<80*128; f+=256){
      int e=f>>7, kk=f&127;
      float v;
      if (e<64){
        if (kk<64) v = g0*c0*kvf[kk*80+e] + g1*c2*kvf[(64+kk)*80+e];
        else { int k2=kk-64; v = g0*c1*kvf[(64+k2)*80+e] + g1*c3*kvf[k2*80+e]; }
      } else if (e==64){
        v = (kk<64) ? kvf[kk*80+64] : kvf[(64+(kk-64))*80+64];
      } else v = 0.f;
      Bm[e*136+kk] = (__bf16)v;
    }
  }
  __syncthreads();
  bf16x8 bF2[5][4];
  #pragma unroll
  for (int nf=0;nf<5;++nf)
    #pragma unroll
    for (int ks=0;ks<4;++ks) bF2[nf][ks] = *(const bf16x8*)&Bm[(nf*16+lr)*136 + ks*32 + lg*8];
  __bf16* At = (__bf16*)plds;
  float* zb = (float*)((char*)plds + 91392);
  for (int pass=0; pass<4; ++pass){
    __syncthreads();
    #pragma unroll
    for (int it=0; it<16; ++it){
      int flat = tid + 256*it;
      int row = flat>>4, dg = flat&15;
      int n = pass*256 + row;
      const float* qr = qkv + ((size_t)(b*1024+n))*1536 + h*64 + dg*4;
      f32x4 u = *(const f32x4*)qr;
      float qp[4], qn[4];
      #pragma unroll
      for (int j=0;j<4;++j) powpair(u[j], pvs[dg*4+j], qp[j], qn[j]);
      *(unsigned*)&At[row*136 + dg*4]        = pk2(qp[0],qp[1]);
      *(unsigned*)&At[row*136 + dg*4+2]      = pk2(qp[2],qp[3]);
      *(unsigned*)&At[row*136 + 64 + dg*4]   = pk2(qn[0],qn[1]);
      *(unsigned*)&At[row*136 + 64 + dg*4+2] = pk2(qn[2],qn[3]);
    }
    __syncthreads();
    f32x4 a2[4][5];
    #pragma unroll
    for (int mf=0;mf<4;++mf)
      #pragma unroll
      for (int nf=0;nf<5;++nf) a2[mf][nf]=fz4();
    #pragma unroll
    for (int ks=0;ks<4;++ks){
      bf16x8 aF[4];
      #pragma unroll
      for (int mf=0;mf<4;++mf) aF[mf] = *(const bf16x8*)&At[(w*64+mf*16+lr)*136 + ks*32 + lg*8];
      #pragma unroll
      for (int nf=0;nf<5;++nf)
        #pragma unroll
        for (int mf=0;mf<4;++mf) a2[mf][nf] = MFMA(aF[mf], bF2[nf][ks], a2[mf][nf]);
    }
    if (lr==0){
      #pragma unroll
      for (int mf=0;mf<4;++mf)
        #pragma unroll
        for (int r=0;r<4;++r) zb[w*64 + mf*16 + lg*4 + r] = a2[mf][4][r] + 1e-6f;
    }
    __syncthreads();
    #pragma unroll
    for (int mf=0;mf<4;++mf){
      float rz[4];
      #pragma unroll
      for (int r=0;r<4;++r) rz[r] = 1.0f / zb[w*64 + mf*16 + lg*4 + r];
      #pragma unroll
      for (int nf=0;nf<4;++nf)
        #pragma unroll
        for (int r=0;r<4;++r){
          int n = pass*256 + w*64 + mf*16 + lg*4 + r;
          int e = nf*16 + lr;
          size_t oi = ((size_t)((b*8+h)*1024) + n)*64 + e;
          float v = a2[mf][nf][r]*rz[r];
          if (s==0) accum[oi] = v; else accum[oi] += v;
        }
    }
  }
}

// ---------------- combined 9x9 depthwise conv ----------------
__global__ __launch_bounds__(256,2) void k_conv(const float* __restrict__ qkv, const float* __restrict__ ws,
                                                float* __restrict__ accum){
  int bid = blockIdx.x;
  int sl = bid & 3, h = (bid>>2)&7, b = bid>>5;
  int tid = threadIdx.x;
  __shared__ float vs[1024][16];
  __shared__ float wc[16][81];
  __shared__ float cb[16];
  for (int it=0; it<64; ++it){
    int flat = tid + 256*it;
    int c = flat & 15, pix = flat>>4;
    vs[pix][c] = qkv[((size_t)(b*1024+pix))*1536 + 1024 + h*64 + sl*16 + c];
  }
  for (int f=tid; f<16*81; f+=256) wc[f/81][f%81] = ws[OFF_CONV9 + (size_t)(sl*16 + f/81)*81 + (f%81)];
  if (tid<16) cb[tid] = ws[OFF_CBIAS + sl*16 + tid];
  __syncthreads();
  #pragma unroll
  for (int cc=0; cc<2; ++cc){
    int col = tid + 256*cc;
    int c = col & 15, x = col >> 4;
    float a[32];
    #pragma unroll
    for (int y=0;y<32;++y) a[y]=0.f;
    #pragma unroll
    for (int dx=-4; dx<=4; ++dx){
      int xx = x+dx;
      bool xv = (xx>=0)&&(xx<32);
      float colv[40];
      #pragma unroll
      for (int i=0;i<40;++i){
        int yy = i-4;
        colv[i] = (xv && yy>=0 && yy<32) ? vs[yy*32+xx][c] : 0.f;
      }
      #pragma unroll
      for (int dy=0; dy<9; ++dy){
        float wv = wc[c][dy*9 + dx+4];
        #pragma unroll
        for (int y=0;y<32;++y) a[y] += wv*colv[y+dy];
      }
    }
    float bias = cb[c];
    #pragma unroll
    for (int y=0;y<32;++y){
      size_t oi = ((size_t)((b*8+h)*1024) + y*32 + x)*64 + sl*16 + c;
      accum[oi] += a[y] + bias;
    }
  }
}

__global__ void k_finalize(const float* __restrict__ accum, float* __restrict__ fin){
  int idx = blockIdx.x*256 + threadIdx.x;
  int c = idx & 511, n = (idx>>9)&1023, b = idx>>19;
  int h = c>>6, d = c&63;
  fin[idx] = accum[((size_t)((b*8+h)*1024)+n)*64 + d] * (1.0f/3.0f);
}

// ---------------- launch ----------------
extern "C" void kernel_launch(void* const* d_in, const int* in_sizes, int n_in,
                              void* d_out, int out_size, void* d_ws, size_t ws_size,
                              hipStream_t stream){
  const float* x        = (const float*)d_in[0];
  const float* qkv_w    = (const float*)d_in[3];
  const float* proj_w   = (const float*)d_in[4];
  const float* proj_b   = (const float*)d_in[5];
  const float* pos_sw   = (const float*)d_in[6];
  const float* neg_sw   = (const float*)d_in[7];
  const float* ca_w1    = (const float*)d_in[9];
  const float* ca_b1    = (const float*)d_in[10];
  const float* ca_w2    = (const float*)d_in[11];
  const float* ca_b2    = (const float*)d_in[12];
  const float* wih_f    = (const float*)d_in[13];
  const float* whh_f    = (const float*)d_in[14];
  const float* bih_f    = (const float*)d_in[15];
  const float* bhh_f    = (const float*)d_in[16];
  const float* wih_b    = (const float*)d_in[17];
  const float* whh_b    = (const float*)d_in[18];
  const float* bih_b    = (const float*)d_in[19];
  const float* bhh_b    = (const float*)d_in[20];
  const float* mha_in_w = (const float*)d_in[21];
  const float* mha_in_b = (const float*)d_in[22];
  const float* mha_out_w= (const float*)d_in[23];
  const float* mha_out_b= (const float*)d_in[24];
  const float* ge_b1    = (const float*)d_in[26];
  const float* ge_w2    = (const float*)d_in[27];
  const float* ge_b2    = (const float*)d_in[28];
  const float* spw      = (const float*)d_in[29];
  const float* w5 = (const float*)d_in[30]; const float* b5 = (const float*)d_in[31];
  const float* w7 = (const float*)d_in[32]; const float* b7 = (const float*)d_in[33];
  const float* w9 = (const float*)d_in[34]; const float* b9 = (const float*)d_in[35];
  const float* mode_w = (const float*)d_in[36];
  float* ws  = (float*)d_ws;
  float* out = (float*)d_out;

  k_const<<<1,256,0,stream>>>(ge_b1, ge_w2, ge_b2, mode_w, w5,b5,w7,b7,w9,b9,
                              pos_sw, neg_sw, spw, bih_f,bhh_f,bih_b,bhh_b, ws);
  // LSTM input gemms (gates in (b,t,512)) -> transpose -> scan
  k_gemm<<<dim3(4,64),256,0,stream>>>(x, wih_f, ws+OFF_LBIAS,     ws+OFF_R0,          8192,512,512);
  k_gemm<<<dim3(4,64),256,0,stream>>>(x, wih_b, ws+OFF_LBIAS+512, ws+OFF_R0+4194304,  8192,512,512);
  k_gxt<<<2048,256,0,stream>>>(ws+OFF_R0, ws+OFF_GXT);
  k_lstm_scan<<<4,512,0,stream>>>(whh_f, whh_b, ws+OFF_GXT, ws+OFF_LC);
  // MHA branch
  k_gemm<<<dim3(12,64),256,0,stream>>>(x, mha_in_w, mha_in_b, ws+OFF_R0, 8192,1536,512);
  k_mha<1><<<dim3(4,4,8),256,0,stream>>>(ws+OFF_R0, ws+OFF_ROWSUM, ws+OFF_COLW);
  k_mha<2><<<dim3(4,4,8),256,0,stream>>>(ws+OFF_R0, ws+OFF_ROWSUM, ws+OFF_COLW);
  k_mha3<<<32,256,0,stream>>>(ws+OFF_R0, ws+OFF_COLW, ws+OFF_ACM);
  k_xmean<<<8,512,0,stream>>>(x, ws+OFF_XMEAN);
  k_coeffs<<<8,256,0,stream>>>(ws, mha_out_w, mha_out_b, ca_w1, ca_b1, ca_w2, ca_b2);
  // scales
  for (int s=0; s<3; ++s){
    k_gemm<<<dim3(12,64),256,0,stream>>>(x, qkv_w + (size_t)s*1536*512, nullptr, ws+OFF_R0, 8192,1536,512);
    k_spec1<<<dim3(2,8,8),256,0,stream>>>(ws+OFF_R0, ws);
    k_spec2<<<dim3(2,8,8),256,0,stream>>>(ws+OFF_R0, ws);
    k_polar<<<dim3(8,8),256,0,stream>>>(ws+OFF_R0, ws, ws+OFF_ACCUM, s);
    k_conv<<<256,256,0,stream>>>(ws+OFF_R0, ws, ws+OFF_ACCUM);
  }
  k_finalize<<<16384,256,0,stream>>>(ws+OFF_ACCUM, ws+OFF_FINAL);
  k_gemm<<<dim3(4,64),256,0,stream>>>(ws+OFF_FINAL, proj_w, proj_b, out, 8192,512,512);
}